// Round 1
// baseline (2421.552 us; speedup 1.0000x reference)
//
#include <hip/hip_runtime.h>
#include <hip/hip_bf16.h>
#include <cstdint>

typedef __bf16 bf16_t;
typedef __bf16 bf16x8 __attribute__((ext_vector_type(8)));
typedef __bf16 bf16x4 __attribute__((ext_vector_type(4)));
typedef float  f32x4  __attribute__((ext_vector_type(4)));

#define B_  2
#define S_  2048
#define D_  2048
#define H_  16
#define DH_ 128

// ---------------------------------------------------------------------------
// async global->LDS (16B per lane, dest = wave-uniform base + lane*16)
__device__ __forceinline__ void gload_lds16(const bf16_t* g, bf16_t* l) {
    __builtin_amdgcn_global_load_lds(
        (const __attribute__((address_space(1))) void*)g,
        (__attribute__((address_space(3))) void*)l, 16, 0, 0);
}

// ---------------------------------------------------------------------------
// fp32 -> bf16 cast, 4 elems/thread, grid sized exactly (n % 1024 == 0)
__global__ __launch_bounds__(256) void cast_bf16_k(const float* __restrict__ in,
                                                   bf16_t* __restrict__ out) {
    long i = ((long)blockIdx.x * blockDim.x + threadIdx.x) * 4;
    float4 v = *(const float4*)(in + i);
    bf16x4 o = {(bf16_t)v.x, (bf16_t)v.y, (bf16_t)v.z, (bf16_t)v.w};
    *(bf16x4*)(out + i) = o;
}

// ---------------------------------------------------------------------------
// NT GEMM: C[M][N] = A[M][K] * B[N][K]^T, bf16 inputs, fp32 accum.
// 128x128 tile, BK=32, 256 threads = 4 waves (2x2), wave = 64x64 out.
// m97-style: global_load_lds staging, [128][32] LDS, ds_read_b128 frags.
template<bool C_BF16>
__global__ __launch_bounds__(256)
void gemm_nt(const bf16_t* __restrict__ A, int lda,
             const bf16_t* __restrict__ B, int ldb,
             void* __restrict__ Cp, int ldc, int coff, int K) {
    __shared__ bf16_t As[128 * 32];
    __shared__ bf16_t Bs[128 * 32];
    const int tid  = threadIdx.x;
    const int wave = tid >> 6;
    const int lane = tid & 63;
    const long bm = (long)blockIdx.y * 128;
    const long bn = (long)blockIdx.x * 128;

    // staging: chunk c covers rows [16c,16c+16); lane l -> row 16c+l/4, col (l&3)*8
    const int srow0 = wave * 16 + (lane >> 2);
    const int srow1 = (4 + wave) * 16 + (lane >> 2);
    const int scol  = (lane & 3) * 8;
    const bf16_t* Ag0 = A + (bm + srow0) * (long)lda + scol;
    const bf16_t* Ag1 = A + (bm + srow1) * (long)lda + scol;
    const bf16_t* Bg0 = B + (bn + srow0) * (long)ldb + scol;
    const bf16_t* Bg1 = B + (bn + srow1) * (long)ldb + scol;
    bf16_t* Al0 = &As[wave * 512];        // wave-uniform LDS dest
    bf16_t* Al1 = &As[(4 + wave) * 512];
    bf16_t* Bl0 = &Bs[wave * 512];
    bf16_t* Bl1 = &Bs[(4 + wave) * 512];

    const int wr = (wave >> 1) * 64;
    const int wc = (wave & 1) * 64;
    const int fr = lane & 15;
    const int ko = (lane >> 4) * 8;

    f32x4 acc[4][4] = {};

    for (int k0 = 0; k0 < K; k0 += 32) {
        gload_lds16(Ag0 + k0, Al0);
        gload_lds16(Ag1 + k0, Al1);
        gload_lds16(Bg0 + k0, Bl0);
        gload_lds16(Bg1 + k0, Bl1);
        __syncthreads();
        bf16x8 a[4], b[4];
#pragma unroll
        for (int i = 0; i < 4; ++i)
            a[i] = *(const bf16x8*)&As[(wr + i * 16 + fr) * 32 + ko];
#pragma unroll
        for (int j = 0; j < 4; ++j)
            b[j] = *(const bf16x8*)&Bs[(wc + j * 16 + fr) * 32 + ko];
#pragma unroll
        for (int i = 0; i < 4; ++i)
#pragma unroll
            for (int j = 0; j < 4; ++j)
                acc[i][j] = __builtin_amdgcn_mfma_f32_16x16x32_bf16(a[i], b[j], acc[i][j], 0, 0, 0);
        __syncthreads();
    }

    // epilogue: D layout col = lane&15, row = (lane>>4)*4 + reg  [verified m89/m91]
#pragma unroll
    for (int i = 0; i < 4; ++i) {
        long r0 = bm + wr + i * 16 + (lane >> 4) * 4;
#pragma unroll
        for (int j = 0; j < 4; ++j) {
            long cc = bn + wc + j * 16 + (lane & 15) + coff;
#pragma unroll
            for (int v = 0; v < 4; ++v) {
                if (C_BF16)
                    ((bf16_t*)Cp)[(r0 + v) * (long)ldc + cc] = (bf16_t)acc[i][j][v];
                else
                    ((float*)Cp)[(r0 + v) * (long)ldc + cc] = acc[i][j][v];
            }
        }
    }
}

// ---------------------------------------------------------------------------
// RoPE for Q and K + reshape (B,S,H*dh) -> (B,H,S,dh). 1 thread per pair.
__global__ __launch_bounds__(256)
void rope_qk_k(const bf16_t* __restrict__ Qp, const bf16_t* __restrict__ Kp,
               const int* __restrict__ pos,
               bf16_t* __restrict__ Qh, bf16_t* __restrict__ Kh) {
    int t = blockIdx.x * 256 + threadIdx.x;   // < B*S*H*64 = 4194304
    int i = t & 63;
    int h = (t >> 6) & 15;
    int s = (t >> 10) & 2047;
    int b = t >> 21;
    long src = ((long)(b * S_ + s)) * D_ + h * DH_ + 2 * i;
    long dst = ((long)((b * H_ + h) * S_ + s)) * DH_ + 2 * i;
    float p = (float)pos[b * S_ + s];
    // inv_freq = 10000^(-2i/128) = exp2(-i * log2(10000)/64)
    float invf = exp2f(-(float)i * 0.20762050593045702f);
    float ang = p * invf;
    float sn, cs;
    sincosf(ang, &sn, &cs);
    float q1 = (float)Qp[src], q2 = (float)Qp[src + 1];
    Qh[dst]     = (bf16_t)(q1 * cs - q2 * sn);
    Qh[dst + 1] = (bf16_t)(q1 * sn + q2 * cs);
    float k1 = (float)Kp[src], k2 = (float)Kp[src + 1];
    Kh[dst]     = (bf16_t)(k1 * cs - k2 * sn);
    Kh[dst + 1] = (bf16_t)(k1 * sn + k2 * cs);
}

// ---------------------------------------------------------------------------
// V reshape+transpose: (B,S,H*dh) -> (B,H,dh,S) via 64x64 LDS tile
__global__ __launch_bounds__(256)
void transpose_v_k(const bf16_t* __restrict__ Vp, bf16_t* __restrict__ Vt) {
    __shared__ bf16_t tile[64][80];   // pad to 160B rows (16B-mult, bank-shifted)
    int t = threadIdx.x;
    int bh = blockIdx.z;
    int b = bh >> 4, h = bh & 15;
    long s0 = (long)blockIdx.x * 64;
    int d0 = blockIdx.y * 64;
    const bf16_t* src = Vp + ((long)b * S_ + s0) * D_ + h * DH_ + d0;
#pragma unroll
    for (int p = 0; p < 2; ++p) {
        int r = (t >> 3) + p * 32;       // s-local
        int c = (t & 7) * 8;             // d-local
        *(bf16x8*)&tile[r][c] = *(const bf16x8*)&src[(long)r * D_ + c];
    }
    __syncthreads();
    bf16_t* dst = Vt + ((long)bh * DH_ + d0) * S_ + s0;
#pragma unroll
    for (int p = 0; p < 2; ++p) {
        int d = (t >> 3) + p * 32;       // d-local
        int c = (t & 7) * 8;             // s-local chunk
        bf16x8 v;
#pragma unroll
        for (int e = 0; e < 8; ++e) v[e] = tile[c + e][d];
        *(bf16x8*)&dst[(long)d * S_ + c] = v;
    }
}

// ---------------------------------------------------------------------------
// causal softmax over one score row: P = softmax(S/sqrt(dh) masked tril), bf16
__global__ __launch_bounds__(256)
void softmax_causal_k(const float* __restrict__ Sc, bf16_t* __restrict__ P) {
    __shared__ float red[8];
    int q = blockIdx.x;
    int t = threadIdx.x;
    const float scale = 0.08838834764831845f;   // 1/sqrt(128)
    const float* row = Sc + (long)q * S_;
    float v[8];
    float4 u0 = *(const float4*)&row[t * 8];
    float4 u1 = *(const float4*)&row[t * 8 + 4];
    v[0] = u0.x; v[1] = u0.y; v[2] = u0.z; v[3] = u0.w;
    v[4] = u1.x; v[5] = u1.y; v[6] = u1.z; v[7] = u1.w;
    float m = -3.0e38f;
#pragma unroll
    for (int e = 0; e < 8; ++e) {
        int k = t * 8 + e;
        v[e] = (k <= q) ? v[e] * scale : -3.0e38f;
        m = fmaxf(m, v[e]);
    }
    for (int o = 32; o; o >>= 1) m = fmaxf(m, __shfl_xor(m, o));
    if ((t & 63) == 0) red[t >> 6] = m;
    __syncthreads();
    m = fmaxf(fmaxf(red[0], red[1]), fmaxf(red[2], red[3]));
    float e8[8];
    float s = 0.f;
#pragma unroll
    for (int e = 0; e < 8; ++e) {
        e8[e] = (t * 8 + e <= q) ? __expf(v[e] - m) : 0.f;
        s += e8[e];
    }
    for (int o = 32; o; o >>= 1) s += __shfl_xor(s, o);
    if ((t & 63) == 0) red[(t >> 6) + 4] = s;
    __syncthreads();
    s = red[4] + red[5] + red[6] + red[7];
    float r = 1.0f / s;
    bf16x8 o;
#pragma unroll
    for (int e = 0; e < 8; ++e) o[e] = (bf16_t)(e8[e] * r);
    *(bf16x8*)&P[(long)q * S_ + t * 8] = o;
}

// ---------------------------------------------------------------------------
extern "C" void kernel_launch(void* const* d_in, const int* in_sizes, int n_in,
                              void* d_out, int out_size, void* d_ws, size_t ws_size,
                              hipStream_t stream) {
    const float* in_features = (const float*)d_in[0];
    const int*   positions   = (const int*)d_in[1];
    // d_in[2] = mask (tril, implemented analytically)
    const float* Wq = (const float*)d_in[3];
    const float* Wk = (const float*)d_in[4];
    const float* Wv = (const float*)d_in[5];
    const float* Wo = (const float*)d_in[6];
    float* out = (float*)d_out;

    const size_t SZ_X = (size_t)B_ * S_ * D_ * 2;   // 16 MB bf16
    const size_t SZ_W = (size_t)D_ * D_ * 2;        // 8 MB bf16
    if (ws_size < SZ_X * 6 + SZ_W * 4) return;      // 151 MB needed

    char* w = (char*)d_ws;
    bf16_t* Xb  = (bf16_t*)w;             w += SZ_X;
    bf16_t* Wqb = (bf16_t*)w;             w += SZ_W;
    bf16_t* Wkb = (bf16_t*)w;             w += SZ_W;
    bf16_t* Wvb = (bf16_t*)w;             w += SZ_W;
    bf16_t* Wob = (bf16_t*)w;             w += SZ_W;
    bf16_t* Qp  = (bf16_t*)w;             w += SZ_X;
    bf16_t* Kp  = (bf16_t*)w;             w += SZ_X;
    bf16_t* Vp  = (bf16_t*)w;             w += SZ_X;
    bf16_t* Qh  = (bf16_t*)w;             w += SZ_X;
    bf16_t* Kh  = (bf16_t*)w;             w += SZ_X;
    bf16_t* Vt  = (bf16_t*)w;             w += SZ_X;
    // aliases onto dead buffers:
    float*  scores  = (float*)Vp;    // Vp dead after transpose (16MB fp32 == 16MB bf16*? both 16.78MB) -- scores = 2048*2048*4 = 16.78MB, Vp slot = 16.78MB  OK
    bf16_t* P       = Kp;            // Kp dead after rope (needs 8.39MB)
    bf16_t* AttnOut = Qp;            // Qp dead after rope (needs 16.78MB)

    // 1. casts
    cast_bf16_k<<<8192, 256, 0, stream>>>(in_features, Xb);
    cast_bf16_k<<<4096, 256, 0, stream>>>(Wq, Wqb);
    cast_bf16_k<<<4096, 256, 0, stream>>>(Wk, Wkb);
    cast_bf16_k<<<4096, 256, 0, stream>>>(Wv, Wvb);
    cast_bf16_k<<<4096, 256, 0, stream>>>(Wo, Wob);

    // 2. QKV projections: (4096 x 2048) = X(4096x2048) * W(2048x2048)^T
    gemm_nt<true><<<dim3(16, 32), 256, 0, stream>>>(Xb, D_, Wqb, D_, Qp, D_, 0, D_);
    gemm_nt<true><<<dim3(16, 32), 256, 0, stream>>>(Xb, D_, Wkb, D_, Kp, D_, 0, D_);
    gemm_nt<true><<<dim3(16, 32), 256, 0, stream>>>(Xb, D_, Wvb, D_, Vp, D_, 0, D_);

    // 3. RoPE + per-head reshape
    rope_qk_k<<<16384, 256, 0, stream>>>(Qp, Kp, positions, Qh, Kh);
    // 4. V transpose to (B,H,dh,S)
    transpose_v_k<<<dim3(32, 2, 32), 256, 0, stream>>>(Vp, Vt);

    // 5. attention per (b,h)
    for (int b = 0; b < B_; ++b)
        for (int h = 0; h < H_; ++h) {
            const bf16_t* Qbh = Qh + ((long)(b * H_ + h)) * S_ * DH_;
            const bf16_t* Kbh = Kh + ((long)(b * H_ + h)) * S_ * DH_;
            const bf16_t* Vbh = Vt + ((long)(b * H_ + h)) * S_ * DH_;
            gemm_nt<false><<<dim3(16, 16), 256, 0, stream>>>(Qbh, DH_, Kbh, DH_,
                                                             scores, S_, 0, DH_);
            softmax_causal_k<<<S_, 256, 0, stream>>>(scores, P);
            gemm_nt<true><<<dim3(1, 16), 256, 0, stream>>>(P, S_, Vbh, S_,
                                                           AttnOut + (long)b * S_ * D_,
                                                           D_, h * DH_, S_);
        }

    // 6. output projection -> fp32 d_out
    gemm_nt<false><<<dim3(16, 32), 256, 0, stream>>>(AttnOut, D_, Wob, D_, out, D_, 0, D_);
}

// Round 2
// 476.875 us; speedup vs baseline: 5.0780x; 5.0780x over previous
//
#include <hip/hip_runtime.h>
#include <hip/hip_bf16.h>
#include <cstdint>

typedef __bf16 bf16_t;
typedef __bf16 bf16x8 __attribute__((ext_vector_type(8)));
typedef __bf16 bf16x4 __attribute__((ext_vector_type(4)));
typedef float  f32x4  __attribute__((ext_vector_type(4)));

#define B_  2
#define S_  2048
#define D_  2048
#define H_  16
#define DH_ 128

// ---------------------------------------------------------------------------
// async global->LDS (16B per lane, dest = wave-uniform base + lane*16)
__device__ __forceinline__ void gload_lds16(const bf16_t* g, bf16_t* l) {
    __builtin_amdgcn_global_load_lds(
        (const __attribute__((address_space(1))) void*)g,
        (__attribute__((address_space(3))) void*)l, 16, 0, 0);
}

// ---------------------------------------------------------------------------
// fp32 -> bf16 cast, 4 elems/thread, grid sized exactly (n % 1024 == 0)
__global__ __launch_bounds__(256) void cast_bf16_k(const float* __restrict__ in,
                                                   bf16_t* __restrict__ out) {
    long i = ((long)blockIdx.x * blockDim.x + threadIdx.x) * 4;
    float4 v = *(const float4*)(in + i);
    bf16x4 o = {(bf16_t)v.x, (bf16_t)v.y, (bf16_t)v.z, (bf16_t)v.w};
    *(bf16x4*)(out + i) = o;
}

// ---------------------------------------------------------------------------
// NT GEMM: C[M][N] = A[M][K] * B[N][K]^T, bf16 in, fp32 accum (m97 structure)
template<bool C_BF16>
__global__ __launch_bounds__(256)
void gemm_nt(const bf16_t* __restrict__ A, int lda,
             const bf16_t* __restrict__ B, int ldb,
             void* __restrict__ Cp, int ldc, int coff, int K) {
    __shared__ bf16_t As[128 * 32];
    __shared__ bf16_t Bs[128 * 32];
    const int tid  = threadIdx.x;
    const int wave = tid >> 6;
    const int lane = tid & 63;
    const long bm = (long)blockIdx.y * 128;
    const long bn = (long)blockIdx.x * 128;

    const int srow0 = wave * 16 + (lane >> 2);
    const int srow1 = (4 + wave) * 16 + (lane >> 2);
    const int scol  = (lane & 3) * 8;
    const bf16_t* Ag0 = A + (bm + srow0) * (long)lda + scol;
    const bf16_t* Ag1 = A + (bm + srow1) * (long)lda + scol;
    const bf16_t* Bg0 = B + (bn + srow0) * (long)ldb + scol;
    const bf16_t* Bg1 = B + (bn + srow1) * (long)ldb + scol;
    bf16_t* Al0 = &As[wave * 512];
    bf16_t* Al1 = &As[(4 + wave) * 512];
    bf16_t* Bl0 = &Bs[wave * 512];
    bf16_t* Bl1 = &Bs[(4 + wave) * 512];

    const int wr = (wave >> 1) * 64;
    const int wc = (wave & 1) * 64;
    const int fr = lane & 15;
    const int ko = (lane >> 4) * 8;

    f32x4 acc[4][4] = {};

    for (int k0 = 0; k0 < K; k0 += 32) {
        gload_lds16(Ag0 + k0, Al0);
        gload_lds16(Ag1 + k0, Al1);
        gload_lds16(Bg0 + k0, Bl0);
        gload_lds16(Bg1 + k0, Bl1);
        __syncthreads();
        bf16x8 a[4], b[4];
#pragma unroll
        for (int i = 0; i < 4; ++i)
            a[i] = *(const bf16x8*)&As[(wr + i * 16 + fr) * 32 + ko];
#pragma unroll
        for (int j = 0; j < 4; ++j)
            b[j] = *(const bf16x8*)&Bs[(wc + j * 16 + fr) * 32 + ko];
#pragma unroll
        for (int i = 0; i < 4; ++i)
#pragma unroll
            for (int j = 0; j < 4; ++j)
                acc[i][j] = __builtin_amdgcn_mfma_f32_16x16x32_bf16(a[i], b[j], acc[i][j], 0, 0, 0);
        __syncthreads();
    }

#pragma unroll
    for (int i = 0; i < 4; ++i) {
        long r0 = bm + wr + i * 16 + (lane >> 4) * 4;
#pragma unroll
        for (int j = 0; j < 4; ++j) {
            long cc = bn + wc + j * 16 + (lane & 15) + coff;
#pragma unroll
            for (int v = 0; v < 4; ++v) {
                if (C_BF16)
                    ((bf16_t*)Cp)[(r0 + v) * (long)ldc + cc] = (bf16_t)acc[i][j][v];
                else
                    ((float*)Cp)[(r0 + v) * (long)ldc + cc] = acc[i][j][v];
            }
        }
    }
}

// ---------------------------------------------------------------------------
// RoPE in place on Qp and Kp, layout (B,S,H*dh). 1 thread per pair.
__global__ __launch_bounds__(256)
void rope_qk_k(bf16_t* __restrict__ Qp, bf16_t* __restrict__ Kp,
               const int* __restrict__ pos) {
    int t = blockIdx.x * 256 + threadIdx.x;   // < B*S*H*64 = 4194304
    int i = t & 63;
    int h = (t >> 6) & 15;
    int s = (t >> 10) & 2047;
    int b = t >> 21;
    long a = ((long)(b * S_ + s)) * D_ + h * DH_ + 2 * i;
    float p = (float)pos[b * S_ + s];
    float invf = exp2f(-(float)i * 0.20762050593045702f);  // 10000^(-2i/128)
    float ang = p * invf;
    float sn, cs;
    sincosf(ang, &sn, &cs);
    float q1 = (float)Qp[a], q2 = (float)Qp[a + 1];
    Qp[a]     = (bf16_t)(q1 * cs - q2 * sn);
    Qp[a + 1] = (bf16_t)(q1 * sn + q2 * cs);
    float k1 = (float)Kp[a], k2 = (float)Kp[a + 1];
    Kp[a]     = (bf16_t)(k1 * cs - k2 * sn);
    Kp[a + 1] = (bf16_t)(k1 * sn + k2 * cs);
}

// ---------------------------------------------------------------------------
// V reshape+transpose: (B,S,H*dh) -> (B,H,dh,S) via 64x64 LDS tile
__global__ __launch_bounds__(256)
void transpose_v_k(const bf16_t* __restrict__ Vp, bf16_t* __restrict__ Vt) {
    __shared__ bf16_t tile[64][80];
    int t = threadIdx.x;
    int bh = blockIdx.z;
    int b = bh >> 4, h = bh & 15;
    long s0 = (long)blockIdx.x * 64;
    int d0 = blockIdx.y * 64;
    const bf16_t* src = Vp + ((long)b * S_ + s0) * D_ + h * DH_ + d0;
#pragma unroll
    for (int p = 0; p < 2; ++p) {
        int r = (t >> 3) + p * 32;
        int c = (t & 7) * 8;
        *(bf16x8*)&tile[r][c] = *(const bf16x8*)&src[(long)r * D_ + c];
    }
    __syncthreads();
    bf16_t* dst = Vt + ((long)bh * DH_ + d0) * S_ + s0;
#pragma unroll
    for (int p = 0; p < 2; ++p) {
        int d = (t >> 3) + p * 32;
        int c = (t & 7) * 8;
        bf16x8 v;
#pragma unroll
        for (int e = 0; e < 8; ++e) v[e] = tile[c + e][d];
        *(bf16x8*)&dst[(long)d * S_ + c] = v;
    }
}

// ---------------------------------------------------------------------------
// swizzled LDS frag read: logical (row, ecol..ecol+7) of a [128][128] bf16 tile
__device__ __forceinline__ bf16x8 ldsw(const bf16_t* p, int row, int ecol) {
    return *(const bf16x8*)(p + row * 128 + (ecol ^ ((row & 7) << 3)));
}

// ---------------------------------------------------------------------------
// Fused causal flash attention.
// Grid: 512 blocks = (qi, b, h); 512 threads = 8 waves, wave w owns q-rows
// [w*16, w*16+16) of its 128-row q-tile. KV tiles of 128, online softmax.
__global__ __launch_bounds__(512, 1)
void flash_attn_k(const bf16_t* __restrict__ Q, const bf16_t* __restrict__ K,
                  const bf16_t* __restrict__ Vt, bf16_t* __restrict__ O) {
    __shared__ bf16_t Ksh[128 * 128];   // [kv][dh]
    __shared__ bf16_t Vsh[128 * 128];   // [dh][kv]  (from Vt)
    __shared__ bf16_t Psh[128 * 128];   // Q staging first, then P

    const int tid  = threadIdx.x;
    const int w    = tid >> 6;
    const int lane = tid & 63;
    const int fr   = lane & 15;
    const int hi   = lane >> 4;
    const int hi8  = hi * 8;
    const int hi4  = hi * 4;
    const int w16  = w * 16;

    const int bid = blockIdx.x;
    const int qi  = 15 - (bid >> 5);      // heavy q-tiles first
    const int bh  = bid & 31;
    const int b   = bh >> 4;
    const int h   = bh & 15;
    const long bS   = (long)b * S_;
    const int  hoff = h * DH_;
    const long vbase = (long)bh * DH_;    // Vt row base (dh rows)

    // ---- stage Q tile (rows qi*128.., head-strided) into Psh, swizzled src
#pragma unroll
    for (int p = 0; p < 4; ++p) {
        int idx = p * 512 + tid;
        int row = idx >> 4;
        int sl  = (idx & 15) ^ (row & 7);
        gload_lds16(Q + (bS + qi * 128 + row) * D_ + hoff + sl * 8,
                    &Psh[(p * 512 + w * 64) * 8]);
    }
    __syncthreads();

    bf16x8 qfrag[4];
#pragma unroll
    for (int kk = 0; kk < 4; ++kk)
        qfrag[kk] = ldsw(Psh, w16 + fr, kk * 32 + hi8);

    f32x4 o[8] = {};
    float m_run[4] = {-3.0e38f, -3.0e38f, -3.0e38f, -3.0e38f};
    float l_run[4] = {};

    const float SC = 0.08838834764831845f * 1.4426950408889634f; // /sqrt(dh)*log2e

    for (int kt = 0; kt <= qi; ++kt) {
        // ---- stage K tile [kv][dh] and V^T tile [dh][kv]
#pragma unroll
        for (int p = 0; p < 4; ++p) {
            int idx = p * 512 + tid;
            int row = idx >> 4;
            int sl  = (idx & 15) ^ (row & 7);
            gload_lds16(K  + (bS + kt * 128 + row) * D_ + hoff + sl * 8,
                        &Ksh[(p * 512 + w * 64) * 8]);
            gload_lds16(Vt + (vbase + row) * S_ + kt * 128 + sl * 8,
                        &Vsh[(p * 512 + w * 64) * 8]);
        }
        __syncthreads();

        // ---- QK^T: wave's 16 q-rows x 128 kv-cols
        f32x4 sc[8];
#pragma unroll
        for (int j = 0; j < 8; ++j) {
            f32x4 z = {};
#pragma unroll
            for (int kk = 0; kk < 4; ++kk)
                z = __builtin_amdgcn_mfma_f32_16x16x32_bf16(
                        qfrag[kk], ldsw(Ksh, j * 16 + fr, kk * 32 + hi8), z, 0, 0, 0);
            sc[j] = z;
        }

        // ---- scale + causal mask (diagonal tile only)
        const bool diag = (kt == qi);
#pragma unroll
        for (int j = 0; j < 8; ++j)
#pragma unroll
            for (int v = 0; v < 4; ++v) {
                float x = sc[j][v] * SC;
                if (diag && (j * 16 + fr > w16 + hi4 + v)) x = -3.0e38f;
                sc[j][v] = x;
            }

        // ---- online softmax (log2 domain), rows = w16+hi4+v
        float fsc[4];
#pragma unroll
        for (int v = 0; v < 4; ++v) {
            float m = fmaxf(fmaxf(fmaxf(sc[0][v], sc[1][v]), fmaxf(sc[2][v], sc[3][v])),
                            fmaxf(fmaxf(sc[4][v], sc[5][v]), fmaxf(sc[6][v], sc[7][v])));
            m = fmaxf(m, __shfl_xor(m, 1));
            m = fmaxf(m, __shfl_xor(m, 2));
            m = fmaxf(m, __shfl_xor(m, 4));
            m = fmaxf(m, __shfl_xor(m, 8));
            float mn = fmaxf(m_run[v], m);
            fsc[v] = exp2f(m_run[v] - mn);
            m_run[v] = mn;
            l_run[v] *= fsc[v];
        }
#pragma unroll
        for (int j2 = 0; j2 < 8; ++j2)
#pragma unroll
            for (int v = 0; v < 4; ++v) o[j2][v] *= fsc[v];

        // ---- P = exp2(sc - m), bf16, to own wave's rows of Psh (swizzled)
#pragma unroll
        for (int j = 0; j < 8; ++j)
#pragma unroll
            for (int v = 0; v < 4; ++v) {
                float p = exp2f(sc[j][v] - m_run[v]);
                l_run[v] += p;
                int row = w16 + hi4 + v;
                int col = j * 16 + fr;
                Psh[row * 128 + (col ^ ((row & 7) << 3))] = (bf16_t)p;
            }

        asm volatile("s_waitcnt lgkmcnt(0)" ::: "memory");

        // ---- PV: O += P[16 x 128] * V[128 kv x 128 dh]  (Vsh is V^T [dh][kv])
        bf16x8 pa[4];
#pragma unroll
        for (int kk = 0; kk < 4; ++kk)
            pa[kk] = ldsw(Psh, w16 + fr, kk * 32 + hi8);
#pragma unroll
        for (int j2 = 0; j2 < 8; ++j2)
#pragma unroll
            for (int kk = 0; kk < 4; ++kk)
                o[j2] = __builtin_amdgcn_mfma_f32_16x16x32_bf16(
                            pa[kk], ldsw(Vsh, j2 * 16 + fr, kk * 32 + hi8), o[j2], 0, 0, 0);

        __syncthreads();   // protect Ksh/Vsh before next stage
    }

    // ---- epilogue: normalize and store (B,S,H*dh)
#pragma unroll
    for (int v = 0; v < 4; ++v) {
        float l = l_run[v];
        l += __shfl_xor(l, 1);
        l += __shfl_xor(l, 2);
        l += __shfl_xor(l, 4);
        l += __shfl_xor(l, 8);
        l_run[v] = 1.0f / l;
    }
    const long orow = bS + qi * 128 + w16 + hi4;
#pragma unroll
    for (int j2 = 0; j2 < 8; ++j2)
#pragma unroll
        for (int v = 0; v < 4; ++v)
            O[(orow + v) * D_ + hoff + j2 * 16 + fr] = (bf16_t)(o[j2][v] * l_run[v]);
}

// ---------------------------------------------------------------------------
extern "C" void kernel_launch(void* const* d_in, const int* in_sizes, int n_in,
                              void* d_out, int out_size, void* d_ws, size_t ws_size,
                              hipStream_t stream) {
    const float* in_features = (const float*)d_in[0];
    const int*   positions   = (const int*)d_in[1];
    // d_in[2] = mask (analytic causal)
    const float* Wq = (const float*)d_in[3];
    const float* Wk = (const float*)d_in[4];
    const float* Wv = (const float*)d_in[5];
    const float* Wo = (const float*)d_in[6];
    float* out = (float*)d_out;

    const size_t SZ_X = (size_t)B_ * S_ * D_ * 2;   // 16.78 MB bf16
    const size_t SZ_W = (size_t)D_ * D_ * 2;        // 8.39 MB bf16
    if (ws_size < SZ_X * 5 + SZ_W * 4) return;      // 117.4 MB needed

    char* w = (char*)d_ws;
    bf16_t* Xb  = (bf16_t*)w;             w += SZ_X;
    bf16_t* Wqb = (bf16_t*)w;             w += SZ_W;
    bf16_t* Wkb = (bf16_t*)w;             w += SZ_W;
    bf16_t* Wvb = (bf16_t*)w;             w += SZ_W;
    bf16_t* Wob = (bf16_t*)w;             w += SZ_W;
    bf16_t* Qp  = (bf16_t*)w;             w += SZ_X;
    bf16_t* Kp  = (bf16_t*)w;             w += SZ_X;
    bf16_t* Vp  = (bf16_t*)w;             w += SZ_X;
    bf16_t* Vt  = (bf16_t*)w;             w += SZ_X;
    bf16_t* AttnOut = Vp;                 // Vp dead after transpose

    // 1. casts
    cast_bf16_k<<<8192, 256, 0, stream>>>(in_features, Xb);
    cast_bf16_k<<<4096, 256, 0, stream>>>(Wq, Wqb);
    cast_bf16_k<<<4096, 256, 0, stream>>>(Wk, Wkb);
    cast_bf16_k<<<4096, 256, 0, stream>>>(Wv, Wvb);
    cast_bf16_k<<<4096, 256, 0, stream>>>(Wo, Wob);

    // 2. QKV projections (4096x2048 = X * W^T)
    gemm_nt<true><<<dim3(16, 32), 256, 0, stream>>>(Xb, D_, Wqb, D_, Qp, D_, 0, D_);
    gemm_nt<true><<<dim3(16, 32), 256, 0, stream>>>(Xb, D_, Wkb, D_, Kp, D_, 0, D_);
    gemm_nt<true><<<dim3(16, 32), 256, 0, stream>>>(Xb, D_, Wvb, D_, Vp, D_, 0, D_);

    // 3. RoPE in place on Q,K
    rope_qk_k<<<16384, 256, 0, stream>>>(Qp, Kp, positions);
    // 4. V transpose to (B,H,dh,S)
    transpose_v_k<<<dim3(32, 2, 32), 256, 0, stream>>>(Vp, Vt);

    // 5. fused causal flash attention -> AttnOut (B,S,H*dh)
    flash_attn_k<<<512, 512, 0, stream>>>(Qp, Kp, Vt, AttnOut);

    // 6. output projection -> fp32 d_out
    gemm_nt<false><<<dim3(16, 32), 256, 0, stream>>>(AttnOut, D_, Wob, D_, out, D_, 0, D_);
}

// Round 5
// 439.023 us; speedup vs baseline: 5.5158x; 1.0862x over previous
//
#include <hip/hip_runtime.h>
#include <hip/hip_bf16.h>
#include <cstdint>

typedef __bf16 bf16_t;
typedef __bf16 bf16x8 __attribute__((ext_vector_type(8)));
typedef __bf16 bf16x4 __attribute__((ext_vector_type(4)));
typedef float  f32x4  __attribute__((ext_vector_type(4)));

#define B_  2
#define S_  2048
#define D_  2048
#define H_  16
#define DH_ 128
#define LDQ 6144   // QKV concat row stride

// ---------------------------------------------------------------------------
// async global->LDS (16B per lane, dest = wave-uniform base + lane*16)
__device__ __forceinline__ void gload_lds16(const bf16_t* g, bf16_t* l) {
    __builtin_amdgcn_global_load_lds(
        (const __attribute__((address_space(1))) void*)g,
        (__attribute__((address_space(3))) void*)l, 16, 0, 0);
}

// ---------------------------------------------------------------------------
// fused fp32 -> bf16 cast of all 5 inputs (X, Wq, Wk, Wv -> Wqkv concat, Wo)
__global__ __launch_bounds__(256)
void cast_all_k(const float* __restrict__ X,  const float* __restrict__ Wq,
                const float* __restrict__ Wk, const float* __restrict__ Wv,
                const float* __restrict__ Wo,
                bf16_t* __restrict__ Xb, bf16_t* __restrict__ Wqkv,
                bf16_t* __restrict__ Wob) {
    long bid = blockIdx.x;
    const float* src; bf16_t* dst; long off;
    if      (bid <  8192) { src = X;  dst = Xb;             off = bid;         }
    else if (bid < 12288) { src = Wq; dst = Wqkv;           off = bid - 8192;  }
    else if (bid < 16384) { src = Wk; dst = Wqkv + 4194304; off = bid - 12288; }
    else if (bid < 20480) { src = Wv; dst = Wqkv + 8388608; off = bid - 16384; }
    else                  { src = Wo; dst = Wob;            off = bid - 20480; }
    long i = (off * 256 + threadIdx.x) * 4;
    float4 v = *(const float4*)(src + i);
    bf16x4 o = {(bf16_t)v.x, (bf16_t)v.y, (bf16_t)v.z, (bf16_t)v.w};
    *(bf16x4*)(dst + i) = o;
}

// ---------------------------------------------------------------------------
// NT GEMM: C[M][N] = A[M][K] * B[N][K]^T, bf16 in, fp32 accum (m97 structure)
// + bijective XCD swizzle on the linear block id (nwg % 8 == 0 required).
template<bool C_BF16>
__global__ __launch_bounds__(256)
void gemm_nt(const bf16_t* __restrict__ A, int lda,
             const bf16_t* __restrict__ B, int ldb,
             void* __restrict__ Cp, int ldc, int K) {
    __shared__ bf16_t As[128 * 32];
    __shared__ bf16_t Bs[128 * 32];
    const int tid  = threadIdx.x;
    const int wave = tid >> 6;
    const int lane = tid & 63;

    const int ntx = gridDim.x;
    const int nwg = ntx * gridDim.y;
    const int lin = blockIdx.y * ntx + blockIdx.x;
    const int swz = (lin & 7) * (nwg >> 3) + (lin >> 3);
    const long bm = (long)(swz / ntx) * 128;
    const long bn = (long)(swz % ntx) * 128;

    const int srow0 = wave * 16 + (lane >> 2);
    const int srow1 = (4 + wave) * 16 + (lane >> 2);
    const int scol  = (lane & 3) * 8;
    const bf16_t* Ag0 = A + (bm + srow0) * (long)lda + scol;
    const bf16_t* Ag1 = A + (bm + srow1) * (long)lda + scol;
    const bf16_t* Bg0 = B + (bn + srow0) * (long)ldb + scol;
    const bf16_t* Bg1 = B + (bn + srow1) * (long)ldb + scol;
    bf16_t* Al0 = &As[wave * 512];
    bf16_t* Al1 = &As[(4 + wave) * 512];
    bf16_t* Bl0 = &Bs[wave * 512];
    bf16_t* Bl1 = &Bs[(4 + wave) * 512];

    const int wr = (wave >> 1) * 64;
    const int wc = (wave & 1) * 64;
    const int fr = lane & 15;
    const int ko = (lane >> 4) * 8;

    f32x4 acc[4][4] = {};

    for (int k0 = 0; k0 < K; k0 += 32) {
        gload_lds16(Ag0 + k0, Al0);
        gload_lds16(Ag1 + k0, Al1);
        gload_lds16(Bg0 + k0, Bl0);
        gload_lds16(Bg1 + k0, Bl1);
        __syncthreads();
        bf16x8 a[4], b[4];
#pragma unroll
        for (int i = 0; i < 4; ++i)
            a[i] = *(const bf16x8*)&As[(wr + i * 16 + fr) * 32 + ko];
#pragma unroll
        for (int j = 0; j < 4; ++j)
            b[j] = *(const bf16x8*)&Bs[(wc + j * 16 + fr) * 32 + ko];
#pragma unroll
        for (int i = 0; i < 4; ++i)
#pragma unroll
            for (int j = 0; j < 4; ++j)
                acc[i][j] = __builtin_amdgcn_mfma_f32_16x16x32_bf16(a[i], b[j], acc[i][j], 0, 0, 0);
        __syncthreads();
    }

#pragma unroll
    for (int i = 0; i < 4; ++i) {
        long r0 = bm + wr + i * 16 + (lane >> 4) * 4;
#pragma unroll
        for (int j = 0; j < 4; ++j) {
            long cc = bn + wc + j * 16 + (lane & 15);
#pragma unroll
            for (int v = 0; v < 4; ++v) {
                if (C_BF16)
                    ((bf16_t*)Cp)[(r0 + v) * (long)ldc + cc] = (bf16_t)acc[i][j][v];
                else
                    ((float*)Cp)[(r0 + v) * (long)ldc + cc] = acc[i][j][v];
            }
        }
    }
}

// ---------------------------------------------------------------------------
// RoPE in place on Q and K regions of QKV [4096][6144]. 4 pairs per thread.
__global__ __launch_bounds__(256)
void rope_qk_k(bf16_t* __restrict__ QKV, const int* __restrict__ pos) {
    int t = blockIdx.x * 256 + threadIdx.x;   // 2^20 threads
    int g = t & 15;            // 4-pair group: pairs 4g..4g+3
    int h = (t >> 4) & 15;
    int s = (t >> 8) & 2047;
    int b = t >> 19;
    long qa = ((long)(b * S_ + s)) * LDQ + h * DH_ + g * 8;
    long ka = qa + D_;
    float p = (float)pos[b * S_ + s];
    bf16x8 q = *(bf16x8*)(QKV + qa);
    bf16x8 k = *(bf16x8*)(QKV + ka);
#pragma unroll
    for (int e = 0; e < 4; ++e) {
        int i = g * 4 + e;     // pair index 0..63
        float invf = exp2f(-(float)i * 0.20762050593045702f);  // 10000^(-2i/128)
        float ang = p * invf;
        float sn, cs;
        __sincosf(ang, &sn, &cs);
        float q1 = (float)q[2 * e], q2 = (float)q[2 * e + 1];
        q[2 * e]     = (bf16_t)(q1 * cs - q2 * sn);
        q[2 * e + 1] = (bf16_t)(q1 * sn + q2 * cs);
        float k1 = (float)k[2 * e], k2 = (float)k[2 * e + 1];
        k[2 * e]     = (bf16_t)(k1 * cs - k2 * sn);
        k[2 * e + 1] = (bf16_t)(k1 * sn + k2 * cs);
    }
    *(bf16x8*)(QKV + qa) = q;
    *(bf16x8*)(QKV + ka) = k;
}

// ---------------------------------------------------------------------------
// V reshape+transpose from QKV cols [4096,6144) -> Vt (B,H,dh,S)
__global__ __launch_bounds__(256)
void transpose_v_k(const bf16_t* __restrict__ QKV, bf16_t* __restrict__ Vt) {
    __shared__ bf16_t tile[64][80];
    int t = threadIdx.x;
    int bh = blockIdx.z;
    int b = bh >> 4, h = bh & 15;
    long s0 = (long)blockIdx.x * 64;
    int d0 = blockIdx.y * 64;
    const bf16_t* src = QKV + ((long)b * S_ + s0) * LDQ + 2 * D_ + h * DH_ + d0;
#pragma unroll
    for (int p = 0; p < 2; ++p) {
        int r = (t >> 3) + p * 32;
        int c = (t & 7) * 8;
        *(bf16x8*)&tile[r][c] = *(const bf16x8*)&src[(long)r * LDQ + c];
    }
    __syncthreads();
    bf16_t* dst = Vt + ((long)bh * DH_ + d0) * S_ + s0;
#pragma unroll
    for (int p = 0; p < 2; ++p) {
        int d = (t >> 3) + p * 32;
        int c = (t & 7) * 8;
        bf16x8 v;
#pragma unroll
        for (int e = 0; e < 8; ++e) v[e] = tile[c + e][d];
        *(bf16x8*)&dst[(long)d * S_ + c] = v;
    }
}

// ---------------------------------------------------------------------------
// swizzled LDS frag read: logical (row, ecol..ecol+7) of a [128][128] bf16 tile
__device__ __forceinline__ bf16x8 ldsw(const bf16_t* p, int row, int ecol) {
    return *(const bf16x8*)(p + row * 128 + (ecol ^ ((row & 7) << 3)));
}

// ---------------------------------------------------------------------------
// Fused causal flash attention, K/V double-buffered with counted vmcnt (T3/T4).
// Grid 512 = (qi heavy-first, b, h); 512 threads = 8 waves x 16 q-rows.
__global__ __launch_bounds__(512, 1)
void flash_attn_k(const bf16_t* __restrict__ QKV, const bf16_t* __restrict__ Vt,
                  bf16_t* __restrict__ O) {
    __shared__ bf16_t Ksh[2][128 * 128];
    __shared__ bf16_t Vsh[2][128 * 128];
    __shared__ bf16_t Psh[128 * 128];      // Q staging, then P

    const int tid  = threadIdx.x;
    const int w    = tid >> 6;
    const int lane = tid & 63;
    const int fr   = lane & 15;
    const int hi   = lane >> 4;
    const int hi8  = hi * 8;
    const int hi4  = hi * 4;
    const int w16  = w * 16;

    const int bid = blockIdx.x;
    const int qi  = 15 - (bid >> 5);      // heavy q-tiles first
    const int bh  = bid & 31;
    const int b   = bh >> 4;
    const int h   = bh & 15;
    const long bS   = (long)b * S_;
    const int  qoff = h * DH_;
    const int  koff = D_ + h * DH_;
    const long vbase = (long)bh * DH_;

    // ---- stage Q -> Psh, and K(0),V(0) -> buf 0
#pragma unroll
    for (int p = 0; p < 4; ++p) {
        int idx = p * 512 + tid;
        int row = idx >> 4;
        int sl  = (idx & 15) ^ (row & 7);
        gload_lds16(QKV + (bS + qi * 128 + row) * (long)LDQ + qoff + sl * 8,
                    &Psh[(p * 512 + w * 64) * 8]);
    }
#pragma unroll
    for (int p = 0; p < 4; ++p) {
        int idx = p * 512 + tid;
        int row = idx >> 4;
        int sl  = (idx & 15) ^ (row & 7);
        gload_lds16(QKV + (bS + row) * (long)LDQ + koff + sl * 8,
                    &Ksh[0][(p * 512 + w * 64) * 8]);
        gload_lds16(Vt + (vbase + row) * S_ + sl * 8,
                    &Vsh[0][(p * 512 + w * 64) * 8]);
    }
    asm volatile("s_waitcnt vmcnt(8)" ::: "memory");   // Q landed; K0/V0 in flight
    __builtin_amdgcn_s_barrier();
    asm volatile("" ::: "memory");

    bf16x8 qfrag[4];
#pragma unroll
    for (int kk = 0; kk < 4; ++kk)
        qfrag[kk] = ldsw(Psh, w16 + fr, kk * 32 + hi8);

    f32x4 o[8] = {};
    float m_run[4] = {-3.0e38f, -3.0e38f, -3.0e38f, -3.0e38f};
    float l_run[4] = {};

    const float SC = 0.08838834764831845f * 1.4426950408889634f; // /sqrt(dh)*log2e

    for (int kt = 0; kt <= qi; ++kt) {
        const int buf = kt & 1;
        // ---- prefetch next tile into other buffer; counted vmcnt (never 0 mid-loop)
        if (kt < qi) {
#pragma unroll
            for (int p = 0; p < 4; ++p) {
                int idx = p * 512 + tid;
                int row = idx >> 4;
                int sl  = (idx & 15) ^ (row & 7);
                gload_lds16(QKV + (bS + (kt + 1) * 128 + row) * (long)LDQ + koff + sl * 8,
                            &Ksh[buf ^ 1][(p * 512 + w * 64) * 8]);
                gload_lds16(Vt + (vbase + row) * S_ + (kt + 1) * 128 + sl * 8,
                            &Vsh[buf ^ 1][(p * 512 + w * 64) * 8]);
            }
            asm volatile("s_waitcnt vmcnt(8)" ::: "memory");  // K(kt),V(kt) done
        } else {
            asm volatile("s_waitcnt vmcnt(0)" ::: "memory");
        }
        __builtin_amdgcn_s_barrier();
        asm volatile("" ::: "memory");

        // ---- QK^T: wave's 16 q-rows x 128 kv-cols
        f32x4 sc[8];
#pragma unroll
        for (int j = 0; j < 8; ++j) {
            f32x4 z = {};
#pragma unroll
            for (int kk = 0; kk < 4; ++kk)
                z = __builtin_amdgcn_mfma_f32_16x16x32_bf16(
                        qfrag[kk], ldsw(Ksh[buf], j * 16 + fr, kk * 32 + hi8), z, 0, 0, 0);
            sc[j] = z;
        }

        // ---- scale + causal mask (diagonal tile only)
        const bool diag = (kt == qi);
#pragma unroll
        for (int j = 0; j < 8; ++j)
#pragma unroll
            for (int v = 0; v < 4; ++v) {
                float x = sc[j][v] * SC;
                if (diag && (j * 16 + fr > w16 + hi4 + v)) x = -3.0e38f;
                sc[j][v] = x;
            }

        // ---- online softmax (log2 domain), rows = w16+hi4+v
        float fsc[4];
#pragma unroll
        for (int v = 0; v < 4; ++v) {
            float m = fmaxf(fmaxf(fmaxf(sc[0][v], sc[1][v]), fmaxf(sc[2][v], sc[3][v])),
                            fmaxf(fmaxf(sc[4][v], sc[5][v]), fmaxf(sc[6][v], sc[7][v])));
            m = fmaxf(m, __shfl_xor(m, 1));
            m = fmaxf(m, __shfl_xor(m, 2));
            m = fmaxf(m, __shfl_xor(m, 4));
            m = fmaxf(m, __shfl_xor(m, 8));
            float mn = fmaxf(m_run[v], m);
            fsc[v] = exp2f(m_run[v] - mn);
            m_run[v] = mn;
            l_run[v] *= fsc[v];
        }
#pragma unroll
        for (int j2 = 0; j2 < 8; ++j2)
#pragma unroll
            for (int v = 0; v < 4; ++v) o[j2][v] *= fsc[v];

        // ---- P = exp2(sc - m) -> own wave's rows of Psh (swizzled)
#pragma unroll
        for (int j = 0; j < 8; ++j)
#pragma unroll
            for (int v = 0; v < 4; ++v) {
                float p = exp2f(sc[j][v] - m_run[v]);
                l_run[v] += p;
                int row = w16 + hi4 + v;
                int col = j * 16 + fr;
                Psh[row * 128 + (col ^ ((row & 7) << 3))] = (bf16_t)p;
            }

        asm volatile("s_waitcnt lgkmcnt(0)" ::: "memory");
        __builtin_amdgcn_sched_barrier(0);

        // ---- PV: O += P[16x128] * V[128x128]  (Vsh is V^T [dh][kv])
        bf16x8 pa[4];
#pragma unroll
        for (int kk = 0; kk < 4; ++kk)
            pa[kk] = ldsw(Psh, w16 + fr, kk * 32 + hi8);
#pragma unroll
        for (int j2 = 0; j2 < 8; ++j2)
#pragma unroll
            for (int kk = 0; kk < 4; ++kk)
                o[j2] = __builtin_amdgcn_mfma_f32_16x16x32_bf16(
                            pa[kk], ldsw(Vsh[buf], j2 * 16 + fr, kk * 32 + hi8), o[j2], 0, 0, 0);

        asm volatile("" ::: "memory");
        __builtin_amdgcn_s_barrier();       // protect buf^1 for next prefetch
        asm volatile("" ::: "memory");
    }

    // ---- epilogue: normalize and store AttnOut (B,S,H*dh)
#pragma unroll
    for (int v = 0; v < 4; ++v) {
        float l = l_run[v];
        l += __shfl_xor(l, 1);
        l += __shfl_xor(l, 2);
        l += __shfl_xor(l, 4);
        l += __shfl_xor(l, 8);
        l_run[v] = 1.0f / l;
    }
    const long orow = bS + qi * 128 + w16 + hi4;
#pragma unroll
    for (int j2 = 0; j2 < 8; ++j2)
#pragma unroll
        for (int v = 0; v < 4; ++v)
            O[(orow + v) * D_ + qoff + j2 * 16 + fr] = (bf16_t)(o[j2][v] * l_run[v]);
}

// ---------------------------------------------------------------------------
extern "C" void kernel_launch(void* const* d_in, const int* in_sizes, int n_in,
                              void* d_out, int out_size, void* d_ws, size_t ws_size,
                              hipStream_t stream) {
    const float* in_features = (const float*)d_in[0];
    const int*   positions   = (const int*)d_in[1];
    // d_in[2] = mask (analytic causal)
    const float* Wq = (const float*)d_in[3];
    const float* Wk = (const float*)d_in[4];
    const float* Wv = (const float*)d_in[5];
    const float* Wo = (const float*)d_in[6];
    float* out = (float*)d_out;

    const size_t SZ_X   = (size_t)B_ * S_ * D_ * 2;    // 16.78 MB
    const size_t SZ_W   = (size_t)D_ * D_ * 2;         // 8.39 MB
    const size_t SZ_QKV = (size_t)B_ * S_ * LDQ * 2;   // 50.33 MB
    if (ws_size < SZ_X * 3 + SZ_W * 4 + SZ_QKV) return;  // 134.2 MB

    char* w = (char*)d_ws;
    bf16_t* Xb      = (bf16_t*)w;   w += SZ_X;
    bf16_t* Wqkv    = (bf16_t*)w;   w += SZ_W * 3;
    bf16_t* Wob     = (bf16_t*)w;   w += SZ_W;
    bf16_t* QKV     = (bf16_t*)w;   w += SZ_QKV;
    bf16_t* Vt      = (bf16_t*)w;   w += SZ_X;
    bf16_t* AttnOut = (bf16_t*)w;   w += SZ_X;

    // 1. fused casts (X, Wq|Wk|Wv -> concat, Wo)
    cast_all_k<<<24576, 256, 0, stream>>>(in_features, Wq, Wk, Wv, Wo, Xb, Wqkv, Wob);

    // 2. merged QKV projection: [4096][6144] = X * Wqkv^T
    gemm_nt<true><<<dim3(48, 32), 256, 0, stream>>>(Xb, D_, Wqkv, D_, QKV, LDQ, D_);

    // 3. RoPE in place on Q,K regions
    rope_qk_k<<<4096, 256, 0, stream>>>(QKV, positions);
    // 4. V transpose to (B,H,dh,S)
    transpose_v_k<<<dim3(32, 2, 32), 256, 0, stream>>>(QKV, Vt);

    // 5. fused causal flash attention -> AttnOut (B,S,H*dh)
    flash_attn_k<<<512, 512, 0, stream>>>(QKV, Vt, AttnOut);

    // 6. output projection -> fp32 d_out
    gemm_nt<false><<<dim3(16, 32), 256, 0, stream>>>(AttnOut, D_, Wob, D_, out, D_, D_);
}

// Round 6
// 425.946 us; speedup vs baseline: 5.6851x; 1.0307x over previous
//
#include <hip/hip_runtime.h>
#include <hip/hip_bf16.h>
#include <cstdint>

typedef __bf16 bf16_t;
typedef __bf16 bf16x8 __attribute__((ext_vector_type(8)));
typedef __bf16 bf16x4 __attribute__((ext_vector_type(4)));
typedef float  f32x4  __attribute__((ext_vector_type(4)));

#define B_  2
#define S_  2048
#define D_  2048
#define H_  16
#define DH_ 128
#define LDQ 6144   // QKV concat row stride

// ---------------------------------------------------------------------------
// async global->LDS (16B per lane, dest = wave-uniform base + lane*16)
__device__ __forceinline__ void gload_lds16(const bf16_t* g, bf16_t* l) {
    __builtin_amdgcn_global_load_lds(
        (const __attribute__((address_space(1))) void*)g,
        (__attribute__((address_space(3))) void*)l, 16, 0, 0);
}

#define BAR  do { asm volatile("" ::: "memory"); __builtin_amdgcn_s_barrier(); \
                  asm volatile("" ::: "memory"); } while (0)
#define WAITLGKM do { asm volatile("s_waitcnt lgkmcnt(0)" ::: "memory"); \
                      __builtin_amdgcn_sched_barrier(0); } while (0)

// ---------------------------------------------------------------------------
// fused fp32 -> bf16 cast of all 5 inputs (X, Wq, Wk, Wv -> Wqkv concat, Wo)
__global__ __launch_bounds__(256)
void cast_all_k(const float* __restrict__ X,  const float* __restrict__ Wq,
                const float* __restrict__ Wk, const float* __restrict__ Wv,
                const float* __restrict__ Wo,
                bf16_t* __restrict__ Xb, bf16_t* __restrict__ Wqkv,
                bf16_t* __restrict__ Wob) {
    long bid = blockIdx.x;
    const float* src; bf16_t* dst; long off;
    if      (bid <  8192) { src = X;  dst = Xb;             off = bid;         }
    else if (bid < 12288) { src = Wq; dst = Wqkv;           off = bid - 8192;  }
    else if (bid < 16384) { src = Wk; dst = Wqkv + 4194304; off = bid - 12288; }
    else if (bid < 20480) { src = Wv; dst = Wqkv + 8388608; off = bid - 16384; }
    else                  { src = Wo; dst = Wob;            off = bid - 20480; }
    long i = (off * 256 + threadIdx.x) * 4;
    float4 v = *(const float4*)(src + i);
    bf16x4 o = {(bf16_t)v.x, (bf16_t)v.y, (bf16_t)v.z, (bf16_t)v.w};
    *(bf16x4*)(dst + i) = o;
}

// ---------------------------------------------------------------------------
// 256x256x64 8-wave phase-split NT GEMM.
// LDS tiles [256][64] bf16, chunk-XOR swizzled (chunk ^= row&7 on 16B chunks),
// staged via global_load_lds with inverse-swizzled global source (rule 21).
// swizzled frag read: logical (row, chunk of 8 elems) of a [256][64] tile
#define LDS8(s, row, chunk) \
    (*(const bf16x8*)((s) + (row) * 64 + ((((chunk) ^ ((row) & 7))) << 3)))

#define MMQ(mh, nh, bfx) \
    _Pragma("unroll") for (int mi = 0; mi < 4; ++mi) { \
      _Pragma("unroll") for (int ni = 0; ni < 2; ++ni) { \
        _Pragma("unroll") for (int ks = 0; ks < 2; ++ks) \
          acc[(mh)*4+mi][(nh)*2+ni] = __builtin_amdgcn_mfma_f32_16x16x32_bf16( \
              af[mi][ks], bfx[ni][ks], acc[(mh)*4+mi][(nh)*2+ni], 0, 0, 0); } }

__device__ __forceinline__ void ktile8(
    const bf16_t* sAc, const bf16_t* sBc,   // compute buffers
    bf16_t* sAn, bf16_t* sBn,               // stage-target buffers
    bool do_stage, long k0s,
    const bf16_t* Agp, const bf16_t* Bgp, int lda, int ldb,
    int wm, int wn, int fr, int hi, int w,
    f32x4 acc[8][4]) {
    bf16x8 af[4][2], bf0[2][2], bf1[2][2];
    // ---- phase 0: A-frags mh=0 (8) + B-frags nh=0 (4); stage next A-tile
#pragma unroll
    for (int mi = 0; mi < 4; ++mi)
#pragma unroll
        for (int ks = 0; ks < 2; ++ks)
            af[mi][ks] = LDS8(sAc, wm * 128 + mi * 16 + fr, ks * 4 + hi);
#pragma unroll
    for (int ni = 0; ni < 2; ++ni)
#pragma unroll
        for (int ks = 0; ks < 2; ++ks)
            bf0[ni][ks] = LDS8(sBc, wn * 64 + ni * 16 + fr, ks * 4 + hi);
    if (do_stage) {
#pragma unroll
        for (int p = 0; p < 4; ++p)
            gload_lds16(Agp + (long)(p * 64) * lda + k0s, sAn + p * 4096 + w * 512);
    }
    BAR; WAITLGKM;
    __builtin_amdgcn_s_setprio(1);
    MMQ(0, 0, bf0);
    __builtin_amdgcn_s_setprio(0);
    BAR;
    // ---- phase 1: B-frags nh=1 (4); stage next B-tile
#pragma unroll
    for (int ni = 0; ni < 2; ++ni)
#pragma unroll
        for (int ks = 0; ks < 2; ++ks)
            bf1[ni][ks] = LDS8(sBc, wn * 64 + 32 + ni * 16 + fr, ks * 4 + hi);
    if (do_stage) {
#pragma unroll
        for (int p = 0; p < 4; ++p)
            gload_lds16(Bgp + (long)(p * 64) * ldb + k0s, sBn + p * 4096 + w * 512);
    }
    BAR; WAITLGKM;
    __builtin_amdgcn_s_setprio(1);
    MMQ(0, 1, bf1);
    __builtin_amdgcn_s_setprio(0);
    BAR;
    // ---- phase 2: A-frags mh=1 (8)
#pragma unroll
    for (int mi = 0; mi < 4; ++mi)
#pragma unroll
        for (int ks = 0; ks < 2; ++ks)
            af[mi][ks] = LDS8(sAc, wm * 128 + 64 + mi * 16 + fr, ks * 4 + hi);
    BAR; WAITLGKM;
    __builtin_amdgcn_s_setprio(1);
    MMQ(1, 0, bf0);
    __builtin_amdgcn_s_setprio(0);
    BAR;
    // ---- phase 3: no ds reads; MFMA; wait staged loads; boundary barrier
    __builtin_amdgcn_s_setprio(1);
    MMQ(1, 1, bf1);
    __builtin_amdgcn_s_setprio(0);
    if (do_stage) asm volatile("s_waitcnt vmcnt(0)" ::: "memory");
    BAR;
}

template<bool C_BF16>
__global__ __launch_bounds__(512, 1)
void gemm_nt8(const bf16_t* __restrict__ A, int lda,
              const bf16_t* __restrict__ B, int ldb,
              void* __restrict__ Cp, int ldc, int K, int nbx) {
    __shared__ bf16_t sA[2][256 * 64];
    __shared__ bf16_t sB[2][256 * 64];
    const int tid  = threadIdx.x;
    const int w    = tid >> 6;
    const int lane = tid & 63;
    const int fr   = lane & 15;
    const int hi   = lane >> 4;
    const int wm   = w >> 2;       // 0..1 (row half)
    const int wn   = w & 3;        // 0..3 (64-col strip)

    const int nwg = gridDim.x;
    const int lin = blockIdx.x;
    const int swz = (lin & 7) * (nwg >> 3) + (lin >> 3);
    const long bm = (long)(swz / nbx) * 256;
    const long bn = (long)(swz % nbx) * 256;

    // staging: thread t covers rows (t>>3)+64p, swizzled 16B chunk (t&7)^(row&7)
    const int  srow = tid >> 3;                         // 0..63
    const int  scol = ((tid & 7) ^ (srow & 7)) * 8;     // elements
    const bf16_t* Agp = A + (bm + srow) * (long)lda + scol;
    const bf16_t* Bgp = B + (bn + srow) * (long)ldb + scol;

    f32x4 acc[8][4] = {};
    const int nkt = K >> 6;   // K-tiles (even)

    // prologue: stage kt0 -> buf 0
#pragma unroll
    for (int p = 0; p < 4; ++p)
        gload_lds16(Agp + (long)(p * 64) * lda, sA[0] + p * 4096 + w * 512);
#pragma unroll
    for (int p = 0; p < 4; ++p)
        gload_lds16(Bgp + (long)(p * 64) * ldb, sB[0] + p * 4096 + w * 512);
    asm volatile("s_waitcnt vmcnt(0)" ::: "memory");
    BAR;

    for (int kt = 0; kt < nkt; kt += 2) {
        ktile8(sA[0], sB[0], sA[1], sB[1], true, (long)(kt + 1) << 6,
               Agp, Bgp, lda, ldb, wm, wn, fr, hi, w, acc);
        ktile8(sA[1], sB[1], sA[0], sB[0], (kt + 2) < nkt, (long)(kt + 2) << 6,
               Agp, Bgp, lda, ldb, wm, wn, fr, hi, w, acc);
    }

    // epilogue: D layout col = lane&15, row = (lane>>4)*4 + reg
#pragma unroll
    for (int m = 0; m < 8; ++m) {
        long r0 = bm + wm * 128 + m * 16 + hi * 4;
#pragma unroll
        for (int n = 0; n < 4; ++n) {
            long cc = bn + wn * 64 + n * 16 + fr;
#pragma unroll
            for (int v = 0; v < 4; ++v) {
                if (C_BF16)
                    ((bf16_t*)Cp)[(r0 + v) * (long)ldc + cc] = (bf16_t)acc[m][n][v];
                else
                    ((float*)Cp)[(r0 + v) * (long)ldc + cc] = acc[m][n][v];
            }
        }
    }
}

// ---------------------------------------------------------------------------
// RoPE in place on Q and K regions of QKV [4096][6144]. 4 pairs per thread.
__global__ __launch_bounds__(256)
void rope_qk_k(bf16_t* __restrict__ QKV, const int* __restrict__ pos) {
    int t = blockIdx.x * 256 + threadIdx.x;   // 2^20 threads
    int g = t & 15;            // 4-pair group: pairs 4g..4g+3
    int h = (t >> 4) & 15;
    int s = (t >> 8) & 2047;
    int b = t >> 19;
    long qa = ((long)(b * S_ + s)) * LDQ + h * DH_ + g * 8;
    long ka = qa + D_;
    float p = (float)pos[b * S_ + s];
    bf16x8 q = *(bf16x8*)(QKV + qa);
    bf16x8 k = *(bf16x8*)(QKV + ka);
#pragma unroll
    for (int e = 0; e < 4; ++e) {
        int i = g * 4 + e;     // pair index 0..63
        float invf = exp2f(-(float)i * 0.20762050593045702f);  // 10000^(-2i/128)
        float ang = p * invf;
        float sn, cs;
        __sincosf(ang, &sn, &cs);
        float q1 = (float)q[2 * e], q2 = (float)q[2 * e + 1];
        q[2 * e]     = (bf16_t)(q1 * cs - q2 * sn);
        q[2 * e + 1] = (bf16_t)(q1 * sn + q2 * cs);
        float k1 = (float)k[2 * e], k2 = (float)k[2 * e + 1];
        k[2 * e]     = (bf16_t)(k1 * cs - k2 * sn);
        k[2 * e + 1] = (bf16_t)(k1 * sn + k2 * cs);
    }
    *(bf16x8*)(QKV + qa) = q;
    *(bf16x8*)(QKV + ka) = k;
}

// ---------------------------------------------------------------------------
// V reshape+transpose from QKV cols [4096,6144) -> Vt (B,H,dh,S)
__global__ __launch_bounds__(256)
void transpose_v_k(const bf16_t* __restrict__ QKV, bf16_t* __restrict__ Vt) {
    __shared__ bf16_t tile[64][80];
    int t = threadIdx.x;
    int bh = blockIdx.z;
    int b = bh >> 4, h = bh & 15;
    long s0 = (long)blockIdx.x * 64;
    int d0 = blockIdx.y * 64;
    const bf16_t* src = QKV + ((long)b * S_ + s0) * LDQ + 2 * D_ + h * DH_ + d0;
#pragma unroll
    for (int p = 0; p < 2; ++p) {
        int r = (t >> 3) + p * 32;
        int c = (t & 7) * 8;
        *(bf16x8*)&tile[r][c] = *(const bf16x8*)&src[(long)r * LDQ + c];
    }
    __syncthreads();
    bf16_t* dst = Vt + ((long)bh * DH_ + d0) * S_ + s0;
#pragma unroll
    for (int p = 0; p < 2; ++p) {
        int d = (t >> 3) + p * 32;
        int c = (t & 7) * 8;
        bf16x8 v;
#pragma unroll
        for (int e = 0; e < 8; ++e) v[e] = tile[c + e][d];
        *(bf16x8*)&dst[(long)d * S_ + c] = v;
    }
}

// ---------------------------------------------------------------------------
// swizzled LDS frag read: logical (row, ecol..ecol+7) of a [128][128] bf16 tile
__device__ __forceinline__ bf16x8 ldsw(const bf16_t* p, int row, int ecol) {
    return *(const bf16x8*)(p + row * 128 + (ecol ^ ((row & 7) << 3)));
}

// ---------------------------------------------------------------------------
// Fused causal flash attention, K/V double-buffered with counted vmcnt (T3/T4).
// Grid 512 = (qi heavy-first, b, h); 512 threads = 8 waves x 16 q-rows.
__global__ __launch_bounds__(512, 1)
void flash_attn_k(const bf16_t* __restrict__ QKV, const bf16_t* __restrict__ Vt,
                  bf16_t* __restrict__ O) {
    __shared__ bf16_t Ksh[2][128 * 128];
    __shared__ bf16_t Vsh[2][128 * 128];
    __shared__ bf16_t Psh[128 * 128];      // Q staging, then P

    const int tid  = threadIdx.x;
    const int w    = tid >> 6;
    const int lane = tid & 63;
    const int fr   = lane & 15;
    const int hi   = lane >> 4;
    const int hi8  = hi * 8;
    const int hi4  = hi * 4;
    const int w16  = w * 16;

    const int bid = blockIdx.x;
    const int qi  = 15 - (bid >> 5);      // heavy q-tiles first
    const int bh  = bid & 31;
    const int b   = bh >> 4;
    const int h   = bh & 15;
    const long bS   = (long)b * S_;
    const int  qoff = h * DH_;
    const int  koff = D_ + h * DH_;
    const long vbase = (long)bh * DH_;

    // ---- stage Q -> Psh, and K(0),V(0) -> buf 0
#pragma unroll
    for (int p = 0; p < 4; ++p) {
        int idx = p * 512 + tid;
        int row = idx >> 4;
        int sl  = (idx & 15) ^ (row & 7);
        gload_lds16(QKV + (bS + qi * 128 + row) * (long)LDQ + qoff + sl * 8,
                    &Psh[(p * 512 + w * 64) * 8]);
    }
#pragma unroll
    for (int p = 0; p < 4; ++p) {
        int idx = p * 512 + tid;
        int row = idx >> 4;
        int sl  = (idx & 15) ^ (row & 7);
        gload_lds16(QKV + (bS + row) * (long)LDQ + koff + sl * 8,
                    &Ksh[0][(p * 512 + w * 64) * 8]);
        gload_lds16(Vt + (vbase + row) * S_ + sl * 8,
                    &Vsh[0][(p * 512 + w * 64) * 8]);
    }
    asm volatile("s_waitcnt vmcnt(8)" ::: "memory");   // Q landed; K0/V0 in flight
    __builtin_amdgcn_s_barrier();
    asm volatile("" ::: "memory");

    bf16x8 qfrag[4];
#pragma unroll
    for (int kk = 0; kk < 4; ++kk)
        qfrag[kk] = ldsw(Psh, w16 + fr, kk * 32 + hi8);

    f32x4 o[8] = {};
    float m_run[4] = {-3.0e38f, -3.0e38f, -3.0e38f, -3.0e38f};
    float l_run[4] = {};

    const float SC = 0.08838834764831845f * 1.4426950408889634f; // /sqrt(dh)*log2e

    for (int kt = 0; kt <= qi; ++kt) {
        const int buf = kt & 1;
        // ---- prefetch next tile into other buffer; counted vmcnt (never 0 mid-loop)
        if (kt < qi) {
#pragma unroll
            for (int p = 0; p < 4; ++p) {
                int idx = p * 512 + tid;
                int row = idx >> 4;
                int sl  = (idx & 15) ^ (row & 7);
                gload_lds16(QKV + (bS + (kt + 1) * 128 + row) * (long)LDQ + koff + sl * 8,
                            &Ksh[buf ^ 1][(p * 512 + w * 64) * 8]);
                gload_lds16(Vt + (vbase + row) * S_ + (kt + 1) * 128 + sl * 8,
                            &Vsh[buf ^ 1][(p * 512 + w * 64) * 8]);
            }
            asm volatile("s_waitcnt vmcnt(8)" ::: "memory");  // K(kt),V(kt) done
        } else {
            asm volatile("s_waitcnt vmcnt(0)" ::: "memory");
        }
        __builtin_amdgcn_s_barrier();
        asm volatile("" ::: "memory");

        // ---- QK^T: wave's 16 q-rows x 128 kv-cols
        f32x4 sc[8];
#pragma unroll
        for (int j = 0; j < 8; ++j) {
            f32x4 z = {};
#pragma unroll
            for (int kk = 0; kk < 4; ++kk)
                z = __builtin_amdgcn_mfma_f32_16x16x32_bf16(
                        qfrag[kk], ldsw(Ksh[buf], j * 16 + fr, kk * 32 + hi8), z, 0, 0, 0);
            sc[j] = z;
        }

        // ---- scale + causal mask (diagonal tile only)
        const bool diag = (kt == qi);
#pragma unroll
        for (int j = 0; j < 8; ++j)
#pragma unroll
            for (int v = 0; v < 4; ++v) {
                float x = sc[j][v] * SC;
                if (diag && (j * 16 + fr > w16 + hi4 + v)) x = -3.0e38f;
                sc[j][v] = x;
            }

        // ---- online softmax (log2 domain), rows = w16+hi4+v
        float fsc[4];
#pragma unroll
        for (int v = 0; v < 4; ++v) {
            float m = fmaxf(fmaxf(fmaxf(sc[0][v], sc[1][v]), fmaxf(sc[2][v], sc[3][v])),
                            fmaxf(fmaxf(sc[4][v], sc[5][v]), fmaxf(sc[6][v], sc[7][v])));
            m = fmaxf(m, __shfl_xor(m, 1));
            m = fmaxf(m, __shfl_xor(m, 2));
            m = fmaxf(m, __shfl_xor(m, 4));
            m = fmaxf(m, __shfl_xor(m, 8));
            float mn = fmaxf(m_run[v], m);
            fsc[v] = exp2f(m_run[v] - mn);
            m_run[v] = mn;
            l_run[v] *= fsc[v];
        }
#pragma unroll
        for (int j2 = 0; j2 < 8; ++j2)
#pragma unroll
            for (int v = 0; v < 4; ++v) o[j2][v] *= fsc[v];

        // ---- P = exp2(sc - m) -> own wave's rows of Psh (swizzled)
#pragma unroll
        for (int j = 0; j < 8; ++j)
#pragma unroll
            for (int v = 0; v < 4; ++v) {
                float p = exp2f(sc[j][v] - m_run[v]);
                l_run[v] += p;
                int row = w16 + hi4 + v;
                int col = j * 16 + fr;
                Psh[row * 128 + (col ^ ((row & 7) << 3))] = (bf16_t)p;
            }

        asm volatile("s_waitcnt lgkmcnt(0)" ::: "memory");
        __builtin_amdgcn_sched_barrier(0);

        // ---- PV: O += P[16x128] * V[128x128]  (Vsh is V^T [dh][kv])
        bf16x8 pa[4];
#pragma unroll
        for (int kk = 0; kk < 4; ++kk)
            pa[kk] = ldsw(Psh, w16 + fr, kk * 32 + hi8);
#pragma unroll
        for (int j2 = 0; j2 < 8; ++j2)
#pragma unroll
            for (int kk = 0; kk < 4; ++kk)
                o[j2] = __builtin_amdgcn_mfma_f32_16x16x32_bf16(
                            pa[kk], ldsw(Vsh[buf], j2 * 16 + fr, kk * 32 + hi8), o[j2], 0, 0, 0);

        asm volatile("" ::: "memory");
        __builtin_amdgcn_s_barrier();       // protect buf^1 for next prefetch
        asm volatile("" ::: "memory");
    }

    // ---- epilogue: normalize and store AttnOut (B,S,H*dh)
#pragma unroll
    for (int v = 0; v < 4; ++v) {
        float l = l_run[v];
        l += __shfl_xor(l, 1);
        l += __shfl_xor(l, 2);
        l += __shfl_xor(l, 4);
        l += __shfl_xor(l, 8);
        l_run[v] = 1.0f / l;
    }
    const long orow = bS + qi * 128 + w16 + hi4;
#pragma unroll
    for (int j2 = 0; j2 < 8; ++j2)
#pragma unroll
        for (int v = 0; v < 4; ++v)
            O[(orow + v) * D_ + qoff + j2 * 16 + fr] = (bf16_t)(o[j2][v] * l_run[v]);
}

// ---------------------------------------------------------------------------
extern "C" void kernel_launch(void* const* d_in, const int* in_sizes, int n_in,
                              void* d_out, int out_size, void* d_ws, size_t ws_size,
                              hipStream_t stream) {
    const float* in_features = (const float*)d_in[0];
    const int*   positions   = (const int*)d_in[1];
    // d_in[2] = mask (analytic causal)
    const float* Wq = (const float*)d_in[3];
    const float* Wk = (const float*)d_in[4];
    const float* Wv = (const float*)d_in[5];
    const float* Wo = (const float*)d_in[6];
    float* out = (float*)d_out;

    const size_t SZ_X   = (size_t)B_ * S_ * D_ * 2;    // 16.78 MB
    const size_t SZ_W   = (size_t)D_ * D_ * 2;         // 8.39 MB
    const size_t SZ_QKV = (size_t)B_ * S_ * LDQ * 2;   // 50.33 MB
    if (ws_size < SZ_X * 3 + SZ_W * 4 + SZ_QKV) return;  // 134.2 MB

    char* w = (char*)d_ws;
    bf16_t* Xb      = (bf16_t*)w;   w += SZ_X;
    bf16_t* Wqkv    = (bf16_t*)w;   w += SZ_W * 3;
    bf16_t* Wob     = (bf16_t*)w;   w += SZ_W;
    bf16_t* QKV     = (bf16_t*)w;   w += SZ_QKV;
    bf16_t* Vt      = (bf16_t*)w;   w += SZ_X;
    bf16_t* AttnOut = (bf16_t*)w;   w += SZ_X;

    // 1. fused casts (X, Wq|Wk|Wv -> concat, Wo)
    cast_all_k<<<24576, 256, 0, stream>>>(in_features, Wq, Wk, Wv, Wo, Xb, Wqkv, Wob);

    // 2. merged QKV projection: [4096][6144] = X * Wqkv^T  (256^2 8-phase)
    gemm_nt8<true><<<384, 512, 0, stream>>>(Xb, D_, Wqkv, D_, QKV, LDQ, D_, 24);

    // 3. RoPE in place on Q,K regions
    rope_qk_k<<<4096, 256, 0, stream>>>(QKV, positions);
    // 4. V transpose to (B,H,dh,S)
    transpose_v_k<<<dim3(32, 2, 32), 256, 0, stream>>>(QKV, Vt);

    // 5. fused causal flash attention -> AttnOut (B,S,H*dh)
    flash_attn_k<<<512, 512, 0, stream>>>(QKV, Vt, AttnOut);

    // 6. output projection -> fp32 d_out  (256^2 8-phase)
    gemm_nt8<false><<<128, 512, 0, stream>>>(AttnOut, D_, Wob, D_, out, D_, D_, 8);
}

// Round 7
// 407.708 us; speedup vs baseline: 5.9394x; 1.0447x over previous
//
#include <hip/hip_runtime.h>
#include <hip/hip_bf16.h>
#include <cstdint>

typedef __bf16 bf16_t;
typedef __bf16 bf16x8 __attribute__((ext_vector_type(8)));
typedef __bf16 bf16x4 __attribute__((ext_vector_type(4)));
typedef float  f32x4  __attribute__((ext_vector_type(4)));

#define B_  2
#define S_  2048
#define D_  2048
#define H_  16
#define DH_ 128
#define LDQ 6144   // QKV concat row stride

// ---------------------------------------------------------------------------
// async global->LDS (16B per lane, dest = wave-uniform base + lane*16)
__device__ __forceinline__ void gload_lds16(const bf16_t* g, bf16_t* l) {
    __builtin_amdgcn_global_load_lds(
        (const __attribute__((address_space(1))) void*)g,
        (__attribute__((address_space(3))) void*)l, 16, 0, 0);
}

#define BAR  do { asm volatile("" ::: "memory"); __builtin_amdgcn_s_barrier(); \
                  asm volatile("" ::: "memory"); } while (0)
#define WAITLGKM do { asm volatile("s_waitcnt lgkmcnt(0)" ::: "memory"); \
                      __builtin_amdgcn_sched_barrier(0); } while (0)

// ---------------------------------------------------------------------------
// fused fp32 -> bf16 cast of all 5 inputs (X, Wq, Wk, Wv -> Wqkv concat, Wo)
__global__ __launch_bounds__(256)
void cast_all_k(const float* __restrict__ X,  const float* __restrict__ Wq,
                const float* __restrict__ Wk, const float* __restrict__ Wv,
                const float* __restrict__ Wo,
                bf16_t* __restrict__ Xb, bf16_t* __restrict__ Wqkv,
                bf16_t* __restrict__ Wob) {
    long bid = blockIdx.x;
    const float* src; bf16_t* dst; long off;
    if      (bid <  8192) { src = X;  dst = Xb;             off = bid;         }
    else if (bid < 12288) { src = Wq; dst = Wqkv;           off = bid - 8192;  }
    else if (bid < 16384) { src = Wk; dst = Wqkv + 4194304; off = bid - 12288; }
    else if (bid < 20480) { src = Wv; dst = Wqkv + 8388608; off = bid - 16384; }
    else                  { src = Wo; dst = Wob;            off = bid - 20480; }
    long i = (off * 256 + threadIdx.x) * 4;
    float4 v = *(const float4*)(src + i);
    bf16x4 o = {(bf16_t)v.x, (bf16_t)v.y, (bf16_t)v.z, (bf16_t)v.w};
    *(bf16x4*)(dst + i) = o;
}

// ---------------------------------------------------------------------------
// NT GEMM, half-tile 4-phase schedule with counted vmcnt (m201-style).
// BM x BN x 64 tile, 8 waves (WMG x WNG), wave tile (BM/WMG) x 64.
// LDS [BM|BN][64] bf16 per buffer, 16B-chunk XOR swizzle (chunk ^= row&7),
// staged via global_load_lds with inverse-swizzled global source.
// Stage slots: p0 -> A1(t+1), p1 -> B0(t+1), p2 -> B1(t+1) into buf^1;
// p3 -> A0(t+2) into buf (its reads finished at p2). Boundary: vmcnt(2).
#define LDS8(s, row, chunk) \
    (*(const bf16x8*)((s) + (row) * 64 + ((((chunk) ^ ((row) & 7))) << 3)))

template<bool C_BF16, int BM, int BN, int WMG, int WNG>
__global__ __launch_bounds__(512, 1)
void gemm_nt9(const bf16_t* __restrict__ A, int lda,
              const bf16_t* __restrict__ B, int ldb,
              void* __restrict__ Cp, int ldc, int K, int nbx) {
    constexpr int WTM = BM / WMG;      // wave tile rows
    constexpr int MR  = WTM / 16;      // m-frags per wave
    constexpr int NR  = 4;             // n-frags per wave (wave cols = 64)
    constexpr int MH  = MR / 2;
    constexpr int NH  = 2;
    constexpr int LA  = BM / 128;      // gloads per thread per A-half
    constexpr int LB  = BN / 128;
    __shared__ bf16_t sA[2][BM * 64];
    __shared__ bf16_t sB[2][BN * 64];

    const int tid  = threadIdx.x;
    const int w    = tid >> 6;
    const int lane = tid & 63;
    const int fr   = lane & 15;
    const int hi   = lane >> 4;
    const int wm   = w / WNG;
    const int wn   = w % WNG;

    const int nwg = gridDim.x;
    const int lin = blockIdx.x;
    const int swz = (lin & 7) * (nwg >> 3) + (lin >> 3);
    const long bm = (long)(swz / nbx) * BM;
    const long bn = (long)(swz % nbx) * BN;

    const int srow = tid >> 3;                       // 0..63
    const int scol = ((tid & 7) ^ (srow & 7)) * 8;   // inverse-swizzled source
    const bf16_t* Agp = A + (bm + srow) * (long)lda + scol;
    const bf16_t* Bgp = B + (bn + srow) * (long)ldb + scol;

#define STAGE_A(bsel, h, kt) { _Pragma("unroll") \
    for (int p = 0; p < LA; ++p) \
        gload_lds16(Agp + (long)((h) * (BM / 2) + p * 64) * lda + ((long)(kt) << 6), \
                    &sA[bsel][((h) * (BM / 2) + p * 64) * 64 + w * 512]); }
#define STAGE_B(bsel, h, kt) { _Pragma("unroll") \
    for (int p = 0; p < LB; ++p) \
        gload_lds16(Bgp + (long)((h) * (BN / 2) + p * 64) * ldb + ((long)(kt) << 6), \
                    &sB[bsel][((h) * (BN / 2) + p * 64) * 64 + w * 512]); }

    f32x4 acc[MR][NR] = {};
    const int nkt = K >> 6;

    // prologue: tile 0 fully into buf0, A0(1) into buf1
    STAGE_A(0, 0, 0) STAGE_A(0, 1, 0)
    STAGE_B(0, 0, 0) STAGE_B(0, 1, 0)
    if (nkt > 1) STAGE_A(1, 0, 1)
    asm volatile("s_waitcnt vmcnt(2)" ::: "memory");
    BAR;

    for (int t = 0; t < nkt; ++t) {
        const int c = t & 1;
        const bf16_t* sAc = sA[c];
        const bf16_t* sBc = sB[c];
        const bool st1 = t + 1 < nkt;
        const bool st2 = t + 2 < nkt;
        bf16x8 af[MH][2], ag[MH][2], bf0[NH][2], bf1[NH][2];

        // ---- phase 0: A-frags mh=0 + B-frags nh=0; stage A1(t+1)
#pragma unroll
        for (int mi = 0; mi < MH; ++mi)
#pragma unroll
            for (int ks = 0; ks < 2; ++ks)
                af[mi][ks] = LDS8(sAc, wm * WTM + mi * 16 + fr, ks * 4 + hi);
#pragma unroll
        for (int ni = 0; ni < NH; ++ni)
#pragma unroll
            for (int ks = 0; ks < 2; ++ks)
                bf0[ni][ks] = LDS8(sBc, wn * 64 + ni * 16 + fr, ks * 4 + hi);
        if (st1) STAGE_A(c ^ 1, 1, t + 1)
        BAR; WAITLGKM;
        __builtin_amdgcn_s_setprio(1);
#pragma unroll
        for (int mi = 0; mi < MH; ++mi)
#pragma unroll
            for (int ni = 0; ni < NH; ++ni)
#pragma unroll
                for (int ks = 0; ks < 2; ++ks)
                    acc[mi][ni] = __builtin_amdgcn_mfma_f32_16x16x32_bf16(
                        af[mi][ks], bf0[ni][ks], acc[mi][ni], 0, 0, 0);
        __builtin_amdgcn_s_setprio(0);
        BAR;

        // ---- phase 1: B-frags nh=1; stage B0(t+1)
#pragma unroll
        for (int ni = 0; ni < NH; ++ni)
#pragma unroll
            for (int ks = 0; ks < 2; ++ks)
                bf1[ni][ks] = LDS8(sBc, wn * 64 + 32 + ni * 16 + fr, ks * 4 + hi);
        if (st1) STAGE_B(c ^ 1, 0, t + 1)
        BAR; WAITLGKM;
        __builtin_amdgcn_s_setprio(1);
#pragma unroll
        for (int mi = 0; mi < MH; ++mi)
#pragma unroll
            for (int ni = 0; ni < NH; ++ni)
#pragma unroll
                for (int ks = 0; ks < 2; ++ks)
                    acc[mi][NH + ni] = __builtin_amdgcn_mfma_f32_16x16x32_bf16(
                        af[mi][ks], bf1[ni][ks], acc[mi][NH + ni], 0, 0, 0);
        __builtin_amdgcn_s_setprio(0);
        BAR;

        // ---- phase 2: A-frags mh=1; stage B1(t+1)
#pragma unroll
        for (int mi = 0; mi < MH; ++mi)
#pragma unroll
            for (int ks = 0; ks < 2; ++ks)
                ag[mi][ks] = LDS8(sAc, wm * WTM + (MH + mi) * 16 + fr, ks * 4 + hi);
        if (st1) STAGE_B(c ^ 1, 1, t + 1)
        BAR; WAITLGKM;
        __builtin_amdgcn_s_setprio(1);
#pragma unroll
        for (int mi = 0; mi < MH; ++mi)
#pragma unroll
            for (int ni = 0; ni < NH; ++ni)
#pragma unroll
                for (int ks = 0; ks < 2; ++ks)
                    acc[MH + mi][ni] = __builtin_amdgcn_mfma_f32_16x16x32_bf16(
                        ag[mi][ks], bf0[ni][ks], acc[MH + mi][ni], 0, 0, 0);
        __builtin_amdgcn_s_setprio(0);
        BAR;

        // ---- phase 3: no ds reads; stage A0(t+2) into buf c; counted wait
        if (st2) STAGE_A(c, 0, t + 2)
        __builtin_amdgcn_s_setprio(1);
#pragma unroll
        for (int mi = 0; mi < MH; ++mi)
#pragma unroll
            for (int ni = 0; ni < NH; ++ni)
#pragma unroll
                for (int ks = 0; ks < 2; ++ks)
                    acc[MH + mi][NH + ni] = __builtin_amdgcn_mfma_f32_16x16x32_bf16(
                        ag[mi][ks], bf1[ni][ks], acc[MH + mi][NH + ni], 0, 0, 0);
        __builtin_amdgcn_s_setprio(0);
        asm volatile("s_waitcnt vmcnt(2)" ::: "memory");   // only A0(t+2) in flight
        BAR;
    }

    // epilogue: D layout col = lane&15, row = (lane>>4)*4 + reg
#pragma unroll
    for (int m = 0; m < MR; ++m) {
        long r0 = bm + wm * WTM + m * 16 + hi * 4;
#pragma unroll
        for (int n = 0; n < NR; ++n) {
            long cc = bn + wn * 64 + n * 16 + fr;
#pragma unroll
            for (int v = 0; v < 4; ++v) {
                if (C_BF16)
                    ((bf16_t*)Cp)[(r0 + v) * (long)ldc + cc] = (bf16_t)acc[m][n][v];
                else
                    ((float*)Cp)[(r0 + v) * (long)ldc + cc] = acc[m][n][v];
            }
        }
    }
#undef STAGE_A
#undef STAGE_B
}

// ---------------------------------------------------------------------------
// RoPE in place on Q and K regions of QKV [4096][6144]. 4 pairs per thread.
__global__ __launch_bounds__(256)
void rope_qk_k(bf16_t* __restrict__ QKV, const int* __restrict__ pos) {
    int t = blockIdx.x * 256 + threadIdx.x;   // 2^20 threads
    int g = t & 15;            // 4-pair group: pairs 4g..4g+3
    int h = (t >> 4) & 15;
    int s = (t >> 8) & 2047;
    int b = t >> 19;
    long qa = ((long)(b * S_ + s)) * LDQ + h * DH_ + g * 8;
    long ka = qa + D_;
    float p = (float)pos[b * S_ + s];
    bf16x8 q = *(bf16x8*)(QKV + qa);
    bf16x8 k = *(bf16x8*)(QKV + ka);
#pragma unroll
    for (int e = 0; e < 4; ++e) {
        int i = g * 4 + e;     // pair index 0..63
        float invf = exp2f(-(float)i * 0.20762050593045702f);  // 10000^(-2i/128)
        float ang = p * invf;
        float sn, cs;
        __sincosf(ang, &sn, &cs);
        float q1 = (float)q[2 * e], q2 = (float)q[2 * e + 1];
        q[2 * e]     = (bf16_t)(q1 * cs - q2 * sn);
        q[2 * e + 1] = (bf16_t)(q1 * sn + q2 * cs);
        float k1 = (float)k[2 * e], k2 = (float)k[2 * e + 1];
        k[2 * e]     = (bf16_t)(k1 * cs - k2 * sn);
        k[2 * e + 1] = (bf16_t)(k1 * sn + k2 * cs);
    }
    *(bf16x8*)(QKV + qa) = q;
    *(bf16x8*)(QKV + ka) = k;
}

// ---------------------------------------------------------------------------
// V reshape+transpose from QKV cols [4096,6144) -> Vt (B,H,dh,S)
__global__ __launch_bounds__(256)
void transpose_v_k(const bf16_t* __restrict__ QKV, bf16_t* __restrict__ Vt) {
    __shared__ bf16_t tile[64][80];
    int t = threadIdx.x;
    int bh = blockIdx.z;
    int b = bh >> 4, h = bh & 15;
    long s0 = (long)blockIdx.x * 64;
    int d0 = blockIdx.y * 64;
    const bf16_t* src = QKV + ((long)b * S_ + s0) * LDQ + 2 * D_ + h * DH_ + d0;
#pragma unroll
    for (int p = 0; p < 2; ++p) {
        int r = (t >> 3) + p * 32;
        int c = (t & 7) * 8;
        *(bf16x8*)&tile[r][c] = *(const bf16x8*)&src[(long)r * LDQ + c];
    }
    __syncthreads();
    bf16_t* dst = Vt + ((long)bh * DH_ + d0) * S_ + s0;
#pragma unroll
    for (int p = 0; p < 2; ++p) {
        int d = (t >> 3) + p * 32;
        int c = (t & 7) * 8;
        bf16x8 v;
#pragma unroll
        for (int e = 0; e < 8; ++e) v[e] = tile[c + e][d];
        *(bf16x8*)&dst[(long)d * S_ + c] = v;
    }
}

// ---------------------------------------------------------------------------
// swizzled LDS frag read: logical (row, ecol..ecol+7) of a [128][128] bf16 tile
__device__ __forceinline__ bf16x8 ldsw(const bf16_t* p, int row, int ecol) {
    return *(const bf16x8*)(p + row * 128 + (ecol ^ ((row & 7) << 3)));
}

// ---------------------------------------------------------------------------
// Fused causal flash attention, K/V double-buffered with counted vmcnt (T3/T4).
// Grid 512 = (qi heavy-first, b, h); 512 threads = 8 waves x 16 q-rows.
__global__ __launch_bounds__(512, 1)
void flash_attn_k(const bf16_t* __restrict__ QKV, const bf16_t* __restrict__ Vt,
                  bf16_t* __restrict__ O) {
    __shared__ bf16_t Ksh[2][128 * 128];
    __shared__ bf16_t Vsh[2][128 * 128];
    __shared__ bf16_t Psh[128 * 128];      // Q staging, then P

    const int tid  = threadIdx.x;
    const int w    = tid >> 6;
    const int lane = tid & 63;
    const int fr   = lane & 15;
    const int hi   = lane >> 4;
    const int hi8  = hi * 8;
    const int hi4  = hi * 4;
    const int w16  = w * 16;

    const int bid = blockIdx.x;
    const int qi  = 15 - (bid >> 5);      // heavy q-tiles first
    const int bh  = bid & 31;
    const int b   = bh >> 4;
    const int h   = bh & 15;
    const long bS   = (long)b * S_;
    const int  qoff = h * DH_;
    const int  koff = D_ + h * DH_;
    const long vbase = (long)bh * DH_;

    // ---- stage Q -> Psh, and K(0),V(0) -> buf 0
#pragma unroll
    for (int p = 0; p < 4; ++p) {
        int idx = p * 512 + tid;
        int row = idx >> 4;
        int sl  = (idx & 15) ^ (row & 7);
        gload_lds16(QKV + (bS + qi * 128 + row) * (long)LDQ + qoff + sl * 8,
                    &Psh[(p * 512 + w * 64) * 8]);
    }
#pragma unroll
    for (int p = 0; p < 4; ++p) {
        int idx = p * 512 + tid;
        int row = idx >> 4;
        int sl  = (idx & 15) ^ (row & 7);
        gload_lds16(QKV + (bS + row) * (long)LDQ + koff + sl * 8,
                    &Ksh[0][(p * 512 + w * 64) * 8]);
        gload_lds16(Vt + (vbase + row) * S_ + sl * 8,
                    &Vsh[0][(p * 512 + w * 64) * 8]);
    }
    asm volatile("s_waitcnt vmcnt(8)" ::: "memory");   // Q landed; K0/V0 in flight
    __builtin_amdgcn_s_barrier();
    asm volatile("" ::: "memory");

    bf16x8 qfrag[4];
#pragma unroll
    for (int kk = 0; kk < 4; ++kk)
        qfrag[kk] = ldsw(Psh, w16 + fr, kk * 32 + hi8);

    f32x4 o[8] = {};
    float m_run[4] = {-3.0e38f, -3.0e38f, -3.0e38f, -3.0e38f};
    float l_run[4] = {};

    const float SC = 0.08838834764831845f * 1.4426950408889634f; // /sqrt(dh)*log2e

    for (int kt = 0; kt <= qi; ++kt) {
        const int buf = kt & 1;
        // ---- prefetch next tile into other buffer; counted vmcnt (never 0 mid-loop)
        if (kt < qi) {
#pragma unroll
            for (int p = 0; p < 4; ++p) {
                int idx = p * 512 + tid;
                int row = idx >> 4;
                int sl  = (idx & 15) ^ (row & 7);
                gload_lds16(QKV + (bS + (kt + 1) * 128 + row) * (long)LDQ + koff + sl * 8,
                            &Ksh[buf ^ 1][(p * 512 + w * 64) * 8]);
                gload_lds16(Vt + (vbase + row) * S_ + (kt + 1) * 128 + sl * 8,
                            &Vsh[buf ^ 1][(p * 512 + w * 64) * 8]);
            }
            asm volatile("s_waitcnt vmcnt(8)" ::: "memory");  // K(kt),V(kt) done
        } else {
            asm volatile("s_waitcnt vmcnt(0)" ::: "memory");
        }
        __builtin_amdgcn_s_barrier();
        asm volatile("" ::: "memory");

        // ---- QK^T: wave's 16 q-rows x 128 kv-cols
        f32x4 sc[8];
#pragma unroll
        for (int j = 0; j < 8; ++j) {
            f32x4 z = {};
#pragma unroll
            for (int kk = 0; kk < 4; ++kk)
                z = __builtin_amdgcn_mfma_f32_16x16x32_bf16(
                        qfrag[kk], ldsw(Ksh[buf], j * 16 + fr, kk * 32 + hi8), z, 0, 0, 0);
            sc[j] = z;
        }

        // ---- scale + causal mask (diagonal tile only)
        const bool diag = (kt == qi);
#pragma unroll
        for (int j = 0; j < 8; ++j)
#pragma unroll
            for (int v = 0; v < 4; ++v) {
                float x = sc[j][v] * SC;
                if (diag && (j * 16 + fr > w16 + hi4 + v)) x = -3.0e38f;
                sc[j][v] = x;
            }

        // ---- online softmax (log2 domain), rows = w16+hi4+v
        float fsc[4];
#pragma unroll
        for (int v = 0; v < 4; ++v) {
            float m = fmaxf(fmaxf(fmaxf(sc[0][v], sc[1][v]), fmaxf(sc[2][v], sc[3][v])),
                            fmaxf(fmaxf(sc[4][v], sc[5][v]), fmaxf(sc[6][v], sc[7][v])));
            m = fmaxf(m, __shfl_xor(m, 1));
            m = fmaxf(m, __shfl_xor(m, 2));
            m = fmaxf(m, __shfl_xor(m, 4));
            m = fmaxf(m, __shfl_xor(m, 8));
            float mn = fmaxf(m_run[v], m);
            fsc[v] = exp2f(m_run[v] - mn);
            m_run[v] = mn;
            l_run[v] *= fsc[v];
        }
#pragma unroll
        for (int j2 = 0; j2 < 8; ++j2)
#pragma unroll
            for (int v = 0; v < 4; ++v) o[j2][v] *= fsc[v];

        // ---- P = exp2(sc - m) -> own wave's rows of Psh (swizzled)
#pragma unroll
        for (int j = 0; j < 8; ++j)
#pragma unroll
            for (int v = 0; v < 4; ++v) {
                float p = exp2f(sc[j][v] - m_run[v]);
                l_run[v] += p;
                int row = w16 + hi4 + v;
                int col = j * 16 + fr;
                Psh[row * 128 + (col ^ ((row & 7) << 3))] = (bf16_t)p;
            }

        asm volatile("s_waitcnt lgkmcnt(0)" ::: "memory");
        __builtin_amdgcn_sched_barrier(0);

        // ---- PV: O += P[16x128] * V[128x128]  (Vsh is V^T [dh][kv])
        bf16x8 pa[4];
#pragma unroll
        for (int kk = 0; kk < 4; ++kk)
            pa[kk] = ldsw(Psh, w16 + fr, kk * 32 + hi8);
#pragma unroll
        for (int j2 = 0; j2 < 8; ++j2)
#pragma unroll
            for (int kk = 0; kk < 4; ++kk)
                o[j2] = __builtin_amdgcn_mfma_f32_16x16x32_bf16(
                            pa[kk], ldsw(Vsh[buf], j2 * 16 + fr, kk * 32 + hi8), o[j2], 0, 0, 0);

        asm volatile("" ::: "memory");
        __builtin_amdgcn_s_barrier();       // protect buf^1 for next prefetch
        asm volatile("" ::: "memory");
    }

    // ---- epilogue: normalize and store AttnOut (B,S,H*dh)
#pragma unroll
    for (int v = 0; v < 4; ++v) {
        float l = l_run[v];
        l += __shfl_xor(l, 1);
        l += __shfl_xor(l, 2);
        l += __shfl_xor(l, 4);
        l += __shfl_xor(l, 8);
        l_run[v] = 1.0f / l;
    }
    const long orow = bS + qi * 128 + w16 + hi4;
#pragma unroll
    for (int j2 = 0; j2 < 8; ++j2)
#pragma unroll
        for (int v = 0; v < 4; ++v)
            O[(orow + v) * D_ + qoff + j2 * 16 + fr] = (bf16_t)(o[j2][v] * l_run[v]);
}

// ---------------------------------------------------------------------------
extern "C" void kernel_launch(void* const* d_in, const int* in_sizes, int n_in,
                              void* d_out, int out_size, void* d_ws, size_t ws_size,
                              hipStream_t stream) {
    const float* in_features = (const float*)d_in[0];
    const int*   positions   = (const int*)d_in[1];
    // d_in[2] = mask (analytic causal)
    const float* Wq = (const float*)d_in[3];
    const float* Wk = (const float*)d_in[4];
    const float* Wv = (const float*)d_in[5];
    const float* Wo = (const float*)d_in[6];
    float* out = (float*)d_out;

    const size_t SZ_X   = (size_t)B_ * S_ * D_ * 2;    // 16.78 MB
    const size_t SZ_W   = (size_t)D_ * D_ * 2;         // 8.39 MB
    const size_t SZ_QKV = (size_t)B_ * S_ * LDQ * 2;   // 50.33 MB
    if (ws_size < SZ_X * 3 + SZ_W * 4 + SZ_QKV) return;  // 134.2 MB

    char* w = (char*)d_ws;
    bf16_t* Xb      = (bf16_t*)w;   w += SZ_X;
    bf16_t* Wqkv    = (bf16_t*)w;   w += SZ_W * 3;
    bf16_t* Wob     = (bf16_t*)w;   w += SZ_W;
    bf16_t* QKV     = (bf16_t*)w;   w += SZ_QKV;
    bf16_t* Vt      = (bf16_t*)w;   w += SZ_X;
    bf16_t* AttnOut = (bf16_t*)w;   w += SZ_X;

    // 1. fused casts (X, Wq|Wk|Wv -> concat, Wo)
    cast_all_k<<<24576, 256, 0, stream>>>(in_features, Wq, Wk, Wv, Wo, Xb, Wqkv, Wob);

    // 2. merged QKV projection: [4096][6144] = X * Wqkv^T  (256^2 half-tile)
    gemm_nt9<true, 256, 256, 2, 4><<<384, 512, 0, stream>>>(Xb, D_, Wqkv, D_,
                                                            QKV, LDQ, D_, 24);

    // 3. RoPE in place on Q,K regions
    rope_qk_k<<<4096, 256, 0, stream>>>(QKV, positions);
    // 4. V transpose to (B,H,dh,S)
    transpose_v_k<<<dim3(32, 2, 32), 256, 0, stream>>>(QKV, Vt);

    // 5. fused causal flash attention -> AttnOut (B,S,H*dh)
    flash_attn_k<<<512, 512, 0, stream>>>(QKV, Vt, AttnOut);

    // 6. output projection -> fp32 d_out  (256x128 tile, 256 blocks = 1/CU even)
    gemm_nt9<false, 256, 128, 4, 2><<<256, 512, 0, stream>>>(AttnOut, D_, Wob, D_,
                                                             out, D_, D_, 16);
}

// Round 10
// 401.423 us; speedup vs baseline: 6.0324x; 1.0157x over previous
//
#include <hip/hip_runtime.h>
#include <hip/hip_bf16.h>
#include <cstdint>

typedef __bf16 bf16_t;
typedef __bf16 bf16x8 __attribute__((ext_vector_type(8)));
typedef __bf16 bf16x4 __attribute__((ext_vector_type(4)));
typedef float  f32x4  __attribute__((ext_vector_type(4)));

#define B_  2
#define S_  2048
#define D_  2048
#define H_  16
#define DH_ 128
#define LDQ 6144   // QKV concat row stride

// ---------------------------------------------------------------------------
// async global->LDS (16B per lane, dest = wave-uniform base + lane*16)
__device__ __forceinline__ void gload_lds16(const bf16_t* g, bf16_t* l) {
    __builtin_amdgcn_global_load_lds(
        (const __attribute__((address_space(1))) void*)g,
        (__attribute__((address_space(3))) void*)l, 16, 0, 0);
}

#define BAR  do { asm volatile("" ::: "memory"); __builtin_amdgcn_s_barrier(); \
                  asm volatile("" ::: "memory"); } while (0)

// ---------------------------------------------------------------------------
// fused fp32 -> bf16 cast of all 5 inputs (X, Wq, Wk, Wv -> Wqkv concat, Wo)
__global__ __launch_bounds__(256)
void cast_all_k(const float* __restrict__ X,  const float* __restrict__ Wq,
                const float* __restrict__ Wk, const float* __restrict__ Wv,
                const float* __restrict__ Wo,
                bf16_t* __restrict__ Xb, bf16_t* __restrict__ Wqkv,
                bf16_t* __restrict__ Wob) {
    long bid = blockIdx.x;
    const float* src; bf16_t* dst; long off;
    if      (bid <  8192) { src = X;  dst = Xb;             off = bid;         }
    else if (bid < 12288) { src = Wq; dst = Wqkv;           off = bid - 8192;  }
    else if (bid < 16384) { src = Wk; dst = Wqkv + 4194304; off = bid - 12288; }
    else if (bid < 20480) { src = Wv; dst = Wqkv + 8388608; off = bid - 16384; }
    else                  { src = Wo; dst = Wob;            off = bid - 20480; }
    long i = (off * 256 + threadIdx.x) * 4;
    float4 v = *(const float4*)(src + i);
    bf16x4 o = {(bf16_t)v.x, (bf16_t)v.y, (bf16_t)v.z, (bf16_t)v.w};
    *(bf16x4*)(dst + i) = o;
}

// ---------------------------------------------------------------------------
// NT GEMM, half-tile 4-phase schedule with counted vmcnt.
// BM x BN x 64 tile, 8 waves (WMG x WNG). LDS XOR-swizzled 16B chunks,
// staged via global_load_lds with inverse-swizzled global source.
// Stage slots: p0 -> A1(t+1), p1 -> B[0..NCB1)(t+1), p2 -> B[NCB1..NCB)(t+1)
// into buf^1; p3 -> A0(t+2) into buf (reads of it finished by p2).
// Boundary wait: vmcnt(2) when A0(t+2) issued, else vmcnt(0).
#define LDS8(s, row, chunk) \
    (*(const bf16x8*)((s) + (row) * 64 + ((((chunk) ^ ((row) & 7))) << 3)))

template<bool C_BF16, int BM, int BN, int WMG, int WNG>
__global__ __launch_bounds__(512, 1)
void gemm_nt9(const bf16_t* __restrict__ A, int lda,
              const bf16_t* __restrict__ B, int ldb,
              void* __restrict__ Cp, int ldc, int K, int nbx) {
    constexpr int MR   = BM / WMG / 16;     // m-frags per wave
    constexpr int NR   = BN / WNG / 16;     // n-frags per wave
    constexpr int MH   = MR / 2;
    constexpr int M2   = MR - MH;
    constexpr int N0   = NR / 2;
    constexpr int N1   = NR - N0;
    constexpr int NCB  = BN / 64;           // B 64-row stage chunks
    constexpr int NCB1 = (NCB + 1) / 2;
    constexpr int WTM  = MR * 16;
    constexpr int WTN  = NR * 16;
    __shared__ bf16_t sA[2][BM * 64];
    __shared__ bf16_t sB[2][BN * 64];

    const int tid  = threadIdx.x;
    const int w    = tid >> 6;
    const int lane = tid & 63;
    const int fr   = lane & 15;
    const int hi   = lane >> 4;
    const int wm   = w / WNG;
    const int wn   = w % WNG;

    const int nwg = gridDim.x;
    const int lin = blockIdx.x;
    const int swz = (lin & 7) * (nwg >> 3) + (lin >> 3);
    const long bm = (long)(swz / nbx) * BM;
    const long bn = (long)(swz % nbx) * BN;

    const int srow = tid >> 3;                       // 0..63
    const int scol = ((tid & 7) ^ (srow & 7)) * 8;   // inverse-swizzled source
    const bf16_t* Agp = A + (bm + srow) * (long)lda + scol;
    const bf16_t* Bgp = B + (bn + srow) * (long)ldb + scol;

#define STAGE_A(bsel, h, kt) { _Pragma("unroll") \
    for (int p = 0; p < 2; ++p) \
        gload_lds16(Agp + (long)((h) * (BM / 2) + p * 64) * lda + ((long)(kt) << 6), \
                    &sA[bsel][((h) * (BM / 2) + p * 64) * 64 + w * 512]); }
#define STAGE_B(bsel, c0, c1, kt) { _Pragma("unroll") \
    for (int p = (c0); p < (c1); ++p) \
        gload_lds16(Bgp + (long)(p * 64) * ldb + ((long)(kt) << 6), \
                    &sB[bsel][(p * 64) * 64 + w * 512]); }

    f32x4 acc[MR][NR] = {};
    const int nkt = K >> 6;

    // prologue: tile 0 fully into buf0, A0(1) into buf1 (K >= 128 assumed)
    STAGE_A(0, 0, 0) STAGE_A(0, 1, 0)
    STAGE_B(0, 0, NCB, 0)
    STAGE_A(1, 0, 1)
    asm volatile("s_waitcnt vmcnt(2)" ::: "memory");
    BAR;

    for (int t = 0; t < nkt; ++t) {
        const int c = t & 1;
        const bf16_t* sAc = sA[c];
        const bf16_t* sBc = sB[c];
        const bool st1 = t + 1 < nkt;
        const bool st2 = t + 2 < nkt;
        bf16x8 af[MH][2], ag[M2][2], bf0[N0][2], bf1[N1][2];

        // ---- phase 0: A-frags mh=0 + B-frags group 0; stage A1(t+1)
#pragma unroll
        for (int mi = 0; mi < MH; ++mi)
#pragma unroll
            for (int ks = 0; ks < 2; ++ks)
                af[mi][ks] = LDS8(sAc, wm * WTM + mi * 16 + fr, ks * 4 + hi);
#pragma unroll
        for (int ni = 0; ni < N0; ++ni)
#pragma unroll
            for (int ks = 0; ks < 2; ++ks)
                bf0[ni][ks] = LDS8(sBc, wn * WTN + ni * 16 + fr, ks * 4 + hi);
        if (st1) STAGE_A(c ^ 1, 1, t + 1)
        BAR;
        __builtin_amdgcn_s_setprio(1);
#pragma unroll
        for (int mi = 0; mi < MH; ++mi)
#pragma unroll
            for (int ni = 0; ni < N0; ++ni)
#pragma unroll
                for (int ks = 0; ks < 2; ++ks)
                    acc[mi][ni] = __builtin_amdgcn_mfma_f32_16x16x32_bf16(
                        af[mi][ks], bf0[ni][ks], acc[mi][ni], 0, 0, 0);
        __builtin_amdgcn_s_setprio(0);
        BAR;

        // ---- phase 1: B-frags group 1; stage B chunks [0,NCB1)(t+1)
#pragma unroll
        for (int ni = 0; ni < N1; ++ni)
#pragma unroll
            for (int ks = 0; ks < 2; ++ks)
                bf1[ni][ks] = LDS8(sBc, wn * WTN + (N0 + ni) * 16 + fr, ks * 4 + hi);
        if (st1) STAGE_B(c ^ 1, 0, NCB1, t + 1)
        BAR;
        __builtin_amdgcn_s_setprio(1);
#pragma unroll
        for (int mi = 0; mi < MH; ++mi)
#pragma unroll
            for (int ni = 0; ni < N1; ++ni)
#pragma unroll
                for (int ks = 0; ks < 2; ++ks)
                    acc[mi][N0 + ni] = __builtin_amdgcn_mfma_f32_16x16x32_bf16(
                        af[mi][ks], bf1[ni][ks], acc[mi][N0 + ni], 0, 0, 0);
        __builtin_amdgcn_s_setprio(0);
        BAR;

        // ---- phase 2: A-frags mh=1; stage B chunks [NCB1,NCB)(t+1)
#pragma unroll
        for (int mi = 0; mi < M2; ++mi)
#pragma unroll
            for (int ks = 0; ks < 2; ++ks)
                ag[mi][ks] = LDS8(sAc, wm * WTM + (MH + mi) * 16 + fr, ks * 4 + hi);
        if (st1) STAGE_B(c ^ 1, NCB1, NCB, t + 1)
        BAR;
        __builtin_amdgcn_s_setprio(1);
#pragma unroll
        for (int mi = 0; mi < M2; ++mi)
#pragma unroll
            for (int ni = 0; ni < N0; ++ni)
#pragma unroll
                for (int ks = 0; ks < 2; ++ks)
                    acc[MH + mi][ni] = __builtin_amdgcn_mfma_f32_16x16x32_bf16(
                        ag[mi][ks], bf0[ni][ks], acc[MH + mi][ni], 0, 0, 0);
        __builtin_amdgcn_s_setprio(0);
        BAR;

        // ---- phase 3: no ds reads; stage A0(t+2) into buf c; counted wait
        if (st2) STAGE_A(c, 0, t + 2)
        __builtin_amdgcn_s_setprio(1);
#pragma unroll
        for (int mi = 0; mi < M2; ++mi)
#pragma unroll
            for (int ni = 0; ni < N1; ++ni)
#pragma unroll
                for (int ks = 0; ks < 2; ++ks)
                    acc[MH + mi][N0 + ni] = __builtin_amdgcn_mfma_f32_16x16x32_bf16(
                        ag[mi][ks], bf1[ni][ks], acc[MH + mi][N0 + ni], 0, 0, 0);
        __builtin_amdgcn_s_setprio(0);
        if (st2) { asm volatile("s_waitcnt vmcnt(2)" ::: "memory"); }
        else     { asm volatile("s_waitcnt vmcnt(0)" ::: "memory"); }
        BAR;
    }

    // epilogue: D layout col = lane&15, row = (lane>>4)*4 + reg
#pragma unroll
    for (int m = 0; m < MR; ++m) {
        long r0 = bm + wm * WTM + m * 16 + hi * 4;
#pragma unroll
        for (int n = 0; n < NR; ++n) {
            long cc = bn + wn * WTN + n * 16 + fr;
#pragma unroll
            for (int v = 0; v < 4; ++v) {
                if (C_BF16)
                    ((bf16_t*)Cp)[(r0 + v) * (long)ldc + cc] = (bf16_t)acc[m][n][v];
                else
                    ((float*)Cp)[(r0 + v) * (long)ldc + cc] = acc[m][n][v];
            }
        }
    }
#undef STAGE_A
#undef STAGE_B
}

// ---------------------------------------------------------------------------
// RoPE in place on Q and K regions of QKV [4096][6144]. 4 pairs per thread.
__global__ __launch_bounds__(256)
void rope_qk_k(bf16_t* __restrict__ QKV, const int* __restrict__ pos) {
    int t = blockIdx.x * 256 + threadIdx.x;   // 2^20 threads
    int g = t & 15;            // 4-pair group: pairs 4g..4g+3
    int h = (t >> 4) & 15;
    int s = (t >> 8) & 2047;
    int b = t >> 19;
    long qa = ((long)(b * S_ + s)) * LDQ + h * DH_ + g * 8;
    long ka = qa + D_;
    float p = (float)pos[b * S_ + s];
    bf16x8 q = *(bf16x8*)(QKV + qa);
    bf16x8 k = *(bf16x8*)(QKV + ka);
#pragma unroll
    for (int e = 0; e < 4; ++e) {
        int i = g * 4 + e;     // pair index 0..63
        float invf = exp2f(-(float)i * 0.20762050593045702f);  // 10000^(-2i/128)
        float ang = p * invf;
        float sn, cs;
        __sincosf(ang, &sn, &cs);
        float q1 = (float)q[2 * e], q2 = (float)q[2 * e + 1];
        q[2 * e]     = (bf16_t)(q1 * cs - q2 * sn);
        q[2 * e + 1] = (bf16_t)(q1 * sn + q2 * cs);
        float k1 = (float)k[2 * e], k2 = (float)k[2 * e + 1];
        k[2 * e]     = (bf16_t)(k1 * cs - k2 * sn);
        k[2 * e + 1] = (bf16_t)(k1 * sn + k2 * cs);
    }
    *(bf16x8*)(QKV + qa) = q;
    *(bf16x8*)(QKV + ka) = k;
}

// ---------------------------------------------------------------------------
// V reshape+transpose from QKV cols [4096,6144) -> Vt (B,H,dh,S)
__global__ __launch_bounds__(256)
void transpose_v_k(const bf16_t* __restrict__ QKV, bf16_t* __restrict__ Vt) {
    __shared__ bf16_t tile[64][80];
    int t = threadIdx.x;
    int bh = blockIdx.z;
    int b = bh >> 4, h = bh & 15;
    long s0 = (long)blockIdx.x * 64;
    int d0 = blockIdx.y * 64;
    const bf16_t* src = QKV + ((long)b * S_ + s0) * LDQ + 2 * D_ + h * DH_ + d0;
#pragma unroll
    for (int p = 0; p < 2; ++p) {
        int r = (t >> 3) + p * 32;
        int c = (t & 7) * 8;
        *(bf16x8*)&tile[r][c] = *(const bf16x8*)&src[(long)r * LDQ + c];
    }
    __syncthreads();
    bf16_t* dst = Vt + ((long)bh * DH_ + d0) * S_ + s0;
#pragma unroll
    for (int p = 0; p < 2; ++p) {
        int d = (t >> 3) + p * 32;
        int c = (t & 7) * 8;
        bf16x8 v;
#pragma unroll
        for (int e = 0; e < 8; ++e) v[e] = tile[c + e][d];
        *(bf16x8*)&dst[(long)d * S_ + c] = v;
    }
}

// ---------------------------------------------------------------------------
// swizzled LDS frag read: logical (row, ecol..ecol+7) of a [128][128] bf16 tile
__device__ __forceinline__ bf16x8 ldsw(const bf16_t* p, int row, int ecol) {
    return *(const bf16x8*)(p + row * 128 + (ecol ^ ((row & 7) << 3)));
}

// ---------------------------------------------------------------------------
// Fused causal flash attention, K/V double-buffered with counted vmcnt (T3/T4).
// Grid 512 = (qi heavy-first, b, h); 512 threads = 8 waves x 16 q-rows.
__global__ __launch_bounds__(512, 1)
void flash_attn_k(const bf16_t* __restrict__ QKV, const bf16_t* __restrict__ Vt,
                  bf16_t* __restrict__ O) {
    __shared__ bf16_t Ksh[2][128 * 128];
    __shared__ bf16_t Vsh[2][128 * 128];
    __shared__ bf16_t Psh[128 * 128];      // Q staging, then P

    const int tid  = threadIdx.x;
    const int w    = tid >> 6;
    const int lane = tid & 63;
    const int fr   = lane & 15;
    const int hi   = lane >> 4;
    const int hi8  = hi * 8;
    const int hi4  = hi * 4;
    const int w16  = w * 16;

    const int bid = blockIdx.x;
    const int qi  = 15 - (bid >> 5);      // heavy q-tiles first
    const int bh  = bid & 31;
    const int b   = bh >> 4;
    const int h   = bh & 15;
    const long bS   = (long)b * S_;
    const int  qoff = h * DH_;
    const int  koff = D_ + h * DH_;
    const long vbase = (long)bh * DH_;

    // ---- stage Q -> Psh, and K(0),V(0) -> buf 0
#pragma unroll
    for (int p = 0; p < 4; ++p) {
        int idx = p * 512 + tid;
        int row = idx >> 4;
        int sl  = (idx & 15) ^ (row & 7);
        gload_lds16(QKV + (bS + qi * 128 + row) * (long)LDQ + qoff + sl * 8,
                    &Psh[(p * 512 + w * 64) * 8]);
    }
#pragma unroll
    for (int p = 0; p < 4; ++p) {
        int idx = p * 512 + tid;
        int row = idx >> 4;
        int sl  = (idx & 15) ^ (row & 7);
        gload_lds16(QKV + (bS + row) * (long)LDQ + koff + sl * 8,
                    &Ksh[0][(p * 512 + w * 64) * 8]);
        gload_lds16(Vt + (vbase + row) * S_ + sl * 8,
                    &Vsh[0][(p * 512 + w * 64) * 8]);
    }
    asm volatile("s_waitcnt vmcnt(8)" ::: "memory");   // Q landed; K0/V0 in flight
    __builtin_amdgcn_s_barrier();
    asm volatile("" ::: "memory");

    bf16x8 qfrag[4];
#pragma unroll
    for (int kk = 0; kk < 4; ++kk)
        qfrag[kk] = ldsw(Psh, w16 + fr, kk * 32 + hi8);

    f32x4 o[8] = {};
    float m_run[4] = {-3.0e38f, -3.0e38f, -3.0e38f, -3.0e38f};
    float l_run[4] = {};

    const float SC = 0.08838834764831845f * 1.4426950408889634f; // /sqrt(dh)*log2e

    for (int kt = 0; kt <= qi; ++kt) {
        const int buf = kt & 1;
        // ---- prefetch next tile into other buffer; counted vmcnt (never 0 mid-loop)
        if (kt < qi) {
#pragma unroll
            for (int p = 0; p < 4; ++p) {
                int idx = p * 512 + tid;
                int row = idx >> 4;
                int sl  = (idx & 15) ^ (row & 7);
                gload_lds16(QKV + (bS + (kt + 1) * 128 + row) * (long)LDQ + koff + sl * 8,
                            &Ksh[buf ^ 1][(p * 512 + w * 64) * 8]);
                gload_lds16(Vt + (vbase + row) * S_ + (kt + 1) * 128 + sl * 8,
                            &Vsh[buf ^ 1][(p * 512 + w * 64) * 8]);
            }
            asm volatile("s_waitcnt vmcnt(8)" ::: "memory");  // K(kt),V(kt) done
        } else {
            asm volatile("s_waitcnt vmcnt(0)" ::: "memory");
        }
        __builtin_amdgcn_s_barrier();
        asm volatile("" ::: "memory");

        // ---- QK^T: wave's 16 q-rows x 128 kv-cols
        f32x4 sc[8];
#pragma unroll
        for (int j = 0; j < 8; ++j) {
            f32x4 z = {};
#pragma unroll
            for (int kk = 0; kk < 4; ++kk)
                z = __builtin_amdgcn_mfma_f32_16x16x32_bf16(
                        qfrag[kk], ldsw(Ksh[buf], j * 16 + fr, kk * 32 + hi8), z, 0, 0, 0);
            sc[j] = z;
        }

        // ---- scale + causal mask (diagonal tile only)
        const bool diag = (kt == qi);
#pragma unroll
        for (int j = 0; j < 8; ++j)
#pragma unroll
            for (int v = 0; v < 4; ++v) {
                float x = sc[j][v] * SC;
                if (diag && (j * 16 + fr > w16 + hi4 + v)) x = -3.0e38f;
                sc[j][v] = x;
            }

        // ---- online softmax (log2 domain), rows = w16+hi4+v
        float fsc[4];
#pragma unroll
        for (int v = 0; v < 4; ++v) {
            float m = fmaxf(fmaxf(fmaxf(sc[0][v], sc[1][v]), fmaxf(sc[2][v], sc[3][v])),
                            fmaxf(fmaxf(sc[4][v], sc[5][v]), fmaxf(sc[6][v], sc[7][v])));
            m = fmaxf(m, __shfl_xor(m, 1));
            m = fmaxf(m, __shfl_xor(m, 2));
            m = fmaxf(m, __shfl_xor(m, 4));
            m = fmaxf(m, __shfl_xor(m, 8));
            float mn = fmaxf(m_run[v], m);
            fsc[v] = exp2f(m_run[v] - mn);
            m_run[v] = mn;
            l_run[v] *= fsc[v];
        }
#pragma unroll
        for (int j2 = 0; j2 < 8; ++j2)
#pragma unroll
            for (int v = 0; v < 4; ++v) o[j2][v] *= fsc[v];

        // ---- P = exp2(sc - m) -> own wave's rows of Psh (swizzled)
#pragma unroll
        for (int j = 0; j < 8; ++j)
#pragma unroll
            for (int v = 0; v < 4; ++v) {
                float p = exp2f(sc[j][v] - m_run[v]);
                l_run[v] += p;
                int row = w16 + hi4 + v;
                int col = j * 16 + fr;
                Psh[row * 128 + (col ^ ((row & 7) << 3))] = (bf16_t)p;
            }

        asm volatile("s_waitcnt lgkmcnt(0)" ::: "memory");
        __builtin_amdgcn_sched_barrier(0);

        // ---- PV: O += P[16x128] * V[128x128]  (Vsh is V^T [dh][kv])
        bf16x8 pa[4];
#pragma unroll
        for (int kk = 0; kk < 4; ++kk)
            pa[kk] = ldsw(Psh, w16 + fr, kk * 32 + hi8);
#pragma unroll
        for (int j2 = 0; j2 < 8; ++j2)
#pragma unroll
            for (int kk = 0; kk < 4; ++kk)
                o[j2] = __builtin_amdgcn_mfma_f32_16x16x32_bf16(
                            pa[kk], ldsw(Vsh[buf], j2 * 16 + fr, kk * 32 + hi8), o[j2], 0, 0, 0);

        asm volatile("" ::: "memory");
        __builtin_amdgcn_s_barrier();       // protect buf^1 for next prefetch
        asm volatile("" ::: "memory");
    }

    // ---- epilogue: normalize and store AttnOut (B,S,H*dh)
#pragma unroll
    for (int v = 0; v < 4; ++v) {
        float l = l_run[v];
        l += __shfl_xor(l, 1);
        l += __shfl_xor(l, 2);
        l += __shfl_xor(l, 4);
        l += __shfl_xor(l, 8);
        l_run[v] = 1.0f / l;
    }
    const long orow = bS + qi * 128 + w16 + hi4;
#pragma unroll
    for (int j2 = 0; j2 < 8; ++j2)
#pragma unroll
        for (int v = 0; v < 4; ++v)
            O[(orow + v) * D_ + qoff + j2 * 16 + fr] = (bf16_t)(o[j2][v] * l_run[v]);
}

// ---------------------------------------------------------------------------
extern "C" void kernel_launch(void* const* d_in, const int* in_sizes, int n_in,
                              void* d_out, int out_size, void* d_ws, size_t ws_size,
                              hipStream_t stream) {
    const float* in_features = (const float*)d_in[0];
    const int*   positions   = (const int*)d_in[1];
    // d_in[2] = mask (analytic causal)
    const float* Wq = (const float*)d_in[3];
    const float* Wk = (const float*)d_in[4];
    const float* Wv = (const float*)d_in[5];
    const float* Wo = (const float*)d_in[6];
    float* out = (float*)d_out;

    const size_t SZ_X   = (size_t)B_ * S_ * D_ * 2;    // 16.78 MB
    const size_t SZ_W   = (size_t)D_ * D_ * 2;         // 8.39 MB
    const size_t SZ_QKV = (size_t)B_ * S_ * LDQ * 2;   // 50.33 MB
    if (ws_size < SZ_X * 3 + SZ_W * 4 + SZ_QKV) return;  // 134.2 MB

    char* w = (char*)d_ws;
    bf16_t* Xb      = (bf16_t*)w;   w += SZ_X;
    bf16_t* Wqkv    = (bf16_t*)w;   w += SZ_W * 3;
    bf16_t* Wob     = (bf16_t*)w;   w += SZ_W;
    bf16_t* QKV     = (bf16_t*)w;   w += SZ_QKV;
    bf16_t* Vt      = (bf16_t*)w;   w += SZ_X;
    bf16_t* AttnOut = (bf16_t*)w;   w += SZ_X;

    // 1. fused casts (X, Wq|Wk|Wv -> concat, Wo)
    cast_all_k<<<24576, 256, 0, stream>>>(in_features, Wq, Wk, Wv, Wo, Xb, Wqkv, Wob);

    // 2. merged QKV projection: [4096][6144] = X * Wqkv^T
    //    256x192 tile -> 16x32 = 512 blocks = exactly 2 even rounds
    gemm_nt9<true, 256, 192, 4, 2><<<512, 512, 0, stream>>>(Xb, D_, Wqkv, D_,
                                                            QKV, LDQ, D_, 32);

    // 3. RoPE in place on Q,K regions
    rope_qk_k<<<4096, 256, 0, stream>>>(QKV, positions);
    // 4. V transpose to (B,H,dh,S)
    transpose_v_k<<<dim3(32, 2, 32), 256, 0, stream>>>(QKV, Vt);

    // 5. fused causal flash attention -> AttnOut (B,S,H*dh)
    flash_attn_k<<<512, 512, 0, stream>>>(QKV, Vt, AttnOut);

    // 6. output projection -> fp32 d_out  (256x128 tile, 256 blocks = 1/CU even)
    gemm_nt9<false, 256, 128, 4, 2><<<256, 512, 0, stream>>>(AttnOut, D_, Wob, D_,
                                                             out, D_, D_, 16);
}